// Round 13
// baseline (2000.870 us; speedup 1.0000x reference)
//
#include <hip/hip_runtime.h>
#include <hip/hip_bf16.h>

#define B_      4
#define TT_     128
#define TA_     512
#define TE_     225
#define T_      865
#define D_      1024
#define H_      16
#define FF_     4096
#define L_      6
#define PREFIX_ 640
#define M_TOK   (B_ * T_)   // 3460
#define M_PAD   3584        // 28 * 128
#define NKV     (L_ * 2 * D_)   // 12288 concat cross K/V rows

typedef __attribute__((ext_vector_type(8))) short          s16x8;
typedef __attribute__((ext_vector_type(4))) float          f32x4;
typedef __attribute__((ext_vector_type(8))) unsigned short u16x8;

typedef __attribute__((address_space(1))) const void gv_t;
typedef __attribute__((address_space(3))) void       lv_t;

__device__ __forceinline__ float bf2f(unsigned short u) {
  union { unsigned int i; float f; } c; c.i = ((unsigned int)u) << 16; return c.f;
}
__device__ __forceinline__ unsigned short f2bf(float f) {
  union { __hip_bfloat16 h; unsigned short u; } c; c.h = __float2bfloat16(f); return c.u;
}
template <int N> __device__ __forceinline__ void vmwait() {
  asm volatile("s_waitcnt vmcnt(%0)" :: "n"(N) : "memory");
}

// ---------------------------------------------------------------------------
// Embedding + pack + PE. Grid = M_PAD rows; padded rows zero the bf16 bufs.
// ---------------------------------------------------------------------------
__global__ __launch_bounds__(256) void embed_kernel(
    const int* __restrict__ text, const int* __restrict__ audio,
    const int* __restrict__ enrolled, const int* __restrict__ tl_b,
    const int* __restrict__ al_b, const float* __restrict__ text_emb,
    const float* __restrict__ audio_emb,
    unsigned short* __restrict__ xb,
    unsigned short* __restrict__ memb, unsigned short* __restrict__ attnb) {
  int row = blockIdx.x;
  int d0 = threadIdx.x * 4;
  size_t off = (size_t)row * D_ + d0;
  if (row >= M_TOK) {
    *(unsigned long long*)&xb[off]    = 0ull;
    *(unsigned long long*)&memb[off]  = 0ull;
    *(unsigned long long*)&attnb[off] = 0ull;
    return;
  }
  int b = row / T_, pos = row - b * T_;
  int tl = tl_b[b], al = al_b[b];
  const float* emb = nullptr;
  int p = 0;
  if (pos < tl) {
    emb = text_emb + (size_t)text[b * TT_ + pos] * D_;
    p = pos;
  } else if (pos < tl + al) {
    emb = audio_emb + (size_t)audio[b * TA_ + (pos - tl)] * D_;
    p = pos - tl;
  } else if (pos < tl + al + TE_) {
    emb = audio_emb + (size_t)enrolled[b * TE_ + (pos - tl - al)] * D_;
    p = pos - tl - al;
  }
  float4 v;
  float* pv = (float*)&v;
  if (emb) {
    const float c = -9.2103403719761836f / (float)D_;  // -ln(10000)/D
    #pragma unroll
    for (int e = 0; e < 4; ++e) {
      int d = d0 + e;
      int i = d >> 1;
      float freq = expf(c * (float)(2 * i));
      float arg = (float)p * freq;
      float pe = (d & 1) ? cosf(arg) : sinf(arg);
      pv[e] = emb[d] + pe;
    }
  } else {
    v = make_float4(0.f, 0.f, 0.f, 0.f);
  }
  unsigned long long pk = (unsigned long long)f2bf(pv[0])
      | ((unsigned long long)f2bf(pv[1]) << 16)
      | ((unsigned long long)f2bf(pv[2]) << 32)
      | ((unsigned long long)f2bf(pv[3]) << 48);
  *(unsigned long long*)&xb[off]   = pk;
  *(unsigned long long*)&memb[off] = pk;
}

// ---------------------------------------------------------------------------
// fp32 -> bf16 converters.
// ---------------------------------------------------------------------------
__global__ __launch_bounds__(256) void cvt_kernel(
    const float* __restrict__ in, unsigned short* __restrict__ out, int n8) {
  int i = blockIdx.x * 256 + threadIdx.x;
  if (i >= n8) return;
  const float4* pp = (const float4*)in + (size_t)i * 2;
  float4 a = pp[0], bq = pp[1];
  u16x8 o;
  o[0] = f2bf(a.x);  o[1] = f2bf(a.y);  o[2] = f2bf(a.z);  o[3] = f2bf(a.w);
  o[4] = f2bf(bq.x); o[5] = f2bf(bq.y); o[6] = f2bf(bq.z); o[7] = f2bf(bq.w);
  *(u16x8*)(out + (size_t)i * 8) = o;
}

__global__ __launch_bounds__(256) void cvt_layer_kernel(
    const float* __restrict__ s0, const float* __restrict__ s1,
    const float* __restrict__ s2, const float* __restrict__ s3,
    const float* __restrict__ s4, const float* __restrict__ s5,
    unsigned short* __restrict__ dst) {
  size_t e = ((size_t)blockIdx.x * 256 + threadIdx.x) * 8;
  if (e >= 16777216u) return;
  const float* src; size_t off;
  if      (e <  3145728u) { src = s0; off = e; }
  else if (e <  4194304u) { src = s1; off = e -  3145728u; }
  else if (e <  7340032u) { src = s2; off = e -  4194304u; }
  else if (e <  8388608u) { src = s3; off = e -  7340032u; }
  else if (e < 12582912u) { src = s4; off = e -  8388608u; }
  else                    { src = s5; off = e - 12582912u; }
  const float4* pp = (const float4*)(src + off);
  float4 a = pp[0], bq = pp[1];
  u16x8 o;
  o[0] = f2bf(a.x);  o[1] = f2bf(a.y);  o[2] = f2bf(a.z);  o[3] = f2bf(a.w);
  o[4] = f2bf(bq.x); o[5] = f2bf(bq.y); o[6] = f2bf(bq.z); o[7] = f2bf(bq.w);
  *(u16x8*)(dst + e) = o;
}

// Gather all 6 layers' cross-attn K,V weight rows -> wckv (NKV x D).
__global__ __launch_bounds__(256) void cvt_ckv_w(
    const float* __restrict__ ca_in_w, unsigned short* __restrict__ wckv) {
  int rr = blockIdx.x;            // 0..NKV-1
  int l = rr / (2 * D_), w = rr % (2 * D_);   // D_+w spans k then v rows
  const float* src = ca_in_w + (size_t)l * 3 * D_ * D_ + (size_t)(D_ + w) * D_;
  unsigned short* dst = wckv + (size_t)rr * D_;
  int c = threadIdx.x * 4;
  float4 v4 = *(const float4*)(src + c);
  unsigned long long pk = (unsigned long long)f2bf(v4.x)
      | ((unsigned long long)f2bf(v4.y) << 16)
      | ((unsigned long long)f2bf(v4.z) << 32)
      | ((unsigned long long)f2bf(v4.w) << 48);
  *(unsigned long long*)&dst[c] = pk;
}

__global__ __launch_bounds__(256) void cvt_ckv_b(
    const float* __restrict__ ca_in_b, float* __restrict__ cbias) {
  int rr = blockIdx.x * 256 + threadIdx.x;
  if (rr >= NKV) return;
  int l = rr / (2 * D_), w = rr % (2 * D_);
  cbias[rr] = ca_in_b[(size_t)l * 3 * D_ + D_ + w];
}

// ---------------------------------------------------------------------------
// 8-wave fat-tile bf16 MFMA GEMM (round-7 proven schedule): 256x256, BK=64.
// ---------------------------------------------------------------------------
template <int ACT, int OBF, int NSTRIPE>
__global__ __launch_bounds__(512, 2) void gemm_8w(
    const unsigned short* __restrict__ A, int lda,
    const unsigned short* __restrict__ W, int ldw,
    const float* __restrict__ bias,
    float* __restrict__ Cf, unsigned short* __restrict__ Cb, int ldc,
    int Mw, int K) {
  __shared__ unsigned short lds[2][2][256 * 64];   // [buf][A|B][row*64+k]
  int tid = threadIdx.x, lane = tid & 63, wid = tid >> 6;

  int gx = gridDim.x;
  int nwg = gx * gridDim.y;
  int orig = blockIdx.y * gx + blockIdx.x;
  int m0, n0;
  if (NSTRIPE && (gx & 7) == 0) {
    int stripe = gx >> 3;
    int xcd = orig & 7, loc = orig >> 3;
    n0 = (xcd * stripe + loc % stripe) * 256;
    m0 = (loc / stripe) * 256;
  } else {
    int q = nwg >> 3, r = nwg & 7;
    int xcd = orig & 7, loc = orig >> 3;
    int wg = (xcd < r ? xcd * (q + 1) : r * (q + 1) + (xcd - r) * q) + loc;
    m0 = (wg / gx) * 256;
    n0 = (wg % gx) * 256;
  }

  int wr = wid >> 2, wc = wid & 3;         // 2 x 4 wave grid
  int r16 = lane & 15, g4 = lane >> 4;

  int srow = lane >> 3;                    // 0..7 within one inst
  int sgrp = (lane & 7) ^ srow;            // inverse-swizzled k-group
  const unsigned short* gA[4];
  const unsigned short* gB[4];
  unsigned soff[4];
  #pragma unroll
  for (int c = 0; c < 4; ++c) {
    int rb = wid * 32 + c * 8;
    gA[c] = A + (size_t)(m0 + rb + srow) * lda + sgrp * 8;
    gB[c] = W + (size_t)(n0 + rb + srow) * ldw + sgrp * 8;
    soff[c] = rb * 64;
  }

  f32x4 acc[8][4];
  #pragma unroll
  for (int i = 0; i < 8; ++i)
    #pragma unroll
    for (int j = 0; j < 4; ++j) acc[i][j] = (f32x4)0.f;

  auto STAGE = [&](int bi, int t) {
    int k0 = t * 64;
    #pragma unroll
    for (int c = 0; c < 4; ++c)
      __builtin_amdgcn_global_load_lds((gv_t*)(gA[c] + k0),
          (lv_t*)&lds[bi][0][soff[c]], 16, 0, 0);
    #pragma unroll
    for (int c = 0; c < 4; ++c)
      __builtin_amdgcn_global_load_lds((gv_t*)(gB[c] + k0),
          (lv_t*)&lds[bi][1][soff[c]], 16, 0, 0);
  };

  STAGE(0, 0);
  int nt = K / 64, cur = 0;
  for (int t = 0; t < nt; ++t) {
    vmwait<0>();                       // tile t landed (issued last iter)
    __builtin_amdgcn_s_barrier();      // everyone past reads of buf cur^1
    if (t + 1 < nt) STAGE(cur ^ 1, t + 1);   // hides under 64 MFMAs below

    const unsigned short* Ab = &lds[cur][0][0];
    const unsigned short* Bb = &lds[cur][1][0];

    s16x8 bf_[4][2];
    #pragma unroll
    for (int j = 0; j < 4; ++j)
      #pragma unroll
      for (int kk = 0; kk < 2; ++kk) {
        int row = wc * 64 + j * 16 + r16;
        bf_[j][kk] = *(const s16x8*)&Bb[row * 64 + (((kk * 4 + g4) ^ (row & 7)) * 8)];
      }

    #pragma unroll
    for (int p = 0; p < 4; ++p) {      // 4 phases x 16 MFMA
      s16x8 af_[2][2];
      #pragma unroll
      for (int ii = 0; ii < 2; ++ii)
        #pragma unroll
        for (int kk = 0; kk < 2; ++kk) {
          int row = wr * 128 + (p * 2 + ii) * 16 + r16;
          af_[ii][kk] = *(const s16x8*)&Ab[row * 64 + (((kk * 4 + g4) ^ (row & 7)) * 8)];
        }
      __builtin_amdgcn_s_setprio(1);
      #pragma unroll
      for (int kk = 0; kk < 2; ++kk)
        #pragma unroll
        for (int ii = 0; ii < 2; ++ii)
          #pragma unroll
          for (int j = 0; j < 4; ++j)
            acc[p * 2 + ii][j] = __builtin_amdgcn_mfma_f32_16x16x32_bf16(
                af_[ii][kk], bf_[j][kk], acc[p * 2 + ii][j], 0, 0, 0);
      __builtin_amdgcn_s_setprio(0);
    }
    cur ^= 1;
  }

  float bv[4];
  #pragma unroll
  for (int j = 0; j < 4; ++j) bv[j] = bias[n0 + wc * 64 + j * 16 + r16];
  int rbase = m0 + wr * 128 + g4 * 4;
  int cbase = n0 + wc * 64 + r16;
  #pragma unroll
  for (int i = 0; i < 8; ++i)
    #pragma unroll
    for (int rr = 0; rr < 4; ++rr) {
      int m = rbase + i * 16 + rr;
      if (m < Mw) {
        #pragma unroll
        for (int j = 0; j < 4; ++j) {
          float v = acc[i][j][rr] + bv[j];
          if (ACT) v = fmaxf(v, 0.f);
          if (OBF) Cb[(size_t)m * ldc + cbase + j * 16] = f2bf(v);
          else     Cf[(size_t)m * ldc + cbase + j * 16] = v;
        }
      }
    }
}

// ---------------------------------------------------------------------------
// 8-wave 128x128 bf16 MFMA GEMM (round-7 schedule). For N<=1024 shapes only.
// ---------------------------------------------------------------------------
template <int ACT, int OBF, int NSTRIPE>
__global__ __launch_bounds__(512, 2) void gemm_8w128(
    const unsigned short* __restrict__ A, int lda,
    const unsigned short* __restrict__ W, int ldw,
    const float* __restrict__ bias,
    float* __restrict__ Cf, unsigned short* __restrict__ Cb, int ldc,
    int Mw, int K) {
  __shared__ unsigned short lds[2][2][128 * 64];   // 64 KB
  int tid = threadIdx.x, lane = tid & 63, wid = tid >> 6;

  int gx = gridDim.x;
  int nwg = gx * gridDim.y;
  int orig = blockIdx.y * gx + blockIdx.x;
  int m0, n0;
  if (NSTRIPE && (gx & 7) == 0) {
    int stripe = gx >> 3;
    int xcd = orig & 7, loc = orig >> 3;
    n0 = (xcd * stripe + loc % stripe) * 128;
    m0 = (loc / stripe) * 128;
  } else {
    int q = nwg >> 3, r = nwg & 7;
    int xcd = orig & 7, loc = orig >> 3;
    int wg = (xcd < r ? xcd * (q + 1) : r * (q + 1) + (xcd - r) * q) + loc;
    m0 = (wg / gx) * 128;
    n0 = (wg % gx) * 128;
  }

  int wr = wid >> 2, wc = wid & 3;         // 2 x 4 wave grid -> 64 x 32 tiles
  int r16 = lane & 15, g4 = lane >> 4;

  int srow = lane >> 3;
  int sgrp = (lane & 7) ^ srow;
  const unsigned short* gA[2];
  const unsigned short* gB[2];
  unsigned soff[2];
  #pragma unroll
  for (int c = 0; c < 2; ++c) {
    int rb = wid * 16 + c * 8;
    gA[c] = A + (size_t)(m0 + rb + srow) * lda + sgrp * 8;
    gB[c] = W + (size_t)(n0 + rb + srow) * ldw + sgrp * 8;
    soff[c] = rb * 64;
  }

  f32x4 acc[4][2];
  #pragma unroll
  for (int i = 0; i < 4; ++i)
    #pragma unroll
    for (int j = 0; j < 2; ++j) acc[i][j] = (f32x4)0.f;

  auto STAGE = [&](int bi, int t) {   // 4 gload_lds per wave
    int k0 = t * 64;
    #pragma unroll
    for (int c = 0; c < 2; ++c)
      __builtin_amdgcn_global_load_lds((gv_t*)(gA[c] + k0),
          (lv_t*)&lds[bi][0][soff[c]], 16, 0, 0);
    #pragma unroll
    for (int c = 0; c < 2; ++c)
      __builtin_amdgcn_global_load_lds((gv_t*)(gB[c] + k0),
          (lv_t*)&lds[bi][1][soff[c]], 16, 0, 0);
  };

  STAGE(0, 0);
  int nt = K / 64, cur = 0;
  for (int t = 0; t < nt; ++t) {
    vmwait<0>();
    __builtin_amdgcn_s_barrier();
    if (t + 1 < nt) STAGE(cur ^ 1, t + 1);

    const unsigned short* Ab = &lds[cur][0][0];
    const unsigned short* Bb = &lds[cur][1][0];

    s16x8 bf_[2][2];
    #pragma unroll
    for (int j = 0; j < 2; ++j)
      #pragma unroll
      for (int kk = 0; kk < 2; ++kk) {
        int row = wc * 32 + j * 16 + r16;
        bf_[j][kk] = *(const s16x8*)&Bb[row * 64 + (((kk * 4 + g4) ^ (row & 7)) * 8)];
      }
    s16x8 af_[4][2];
    #pragma unroll
    for (int ii = 0; ii < 4; ++ii)
      #pragma unroll
      for (int kk = 0; kk < 2; ++kk) {
        int row = wr * 64 + ii * 16 + r16;
        af_[ii][kk] = *(const s16x8*)&Ab[row * 64 + (((kk * 4 + g4) ^ (row & 7)) * 8)];
      }
    __builtin_amdgcn_s_setprio(1);
    #pragma unroll
    for (int kk = 0; kk < 2; ++kk)
      #pragma unroll
      for (int ii = 0; ii < 4; ++ii)
        #pragma unroll
        for (int j = 0; j < 2; ++j)
          acc[ii][j] = __builtin_amdgcn_mfma_f32_16x16x32_bf16(
              af_[ii][kk], bf_[j][kk], acc[ii][j], 0, 0, 0);
    __builtin_amdgcn_s_setprio(0);
    cur ^= 1;
  }

  float bv[2];
  #pragma unroll
  for (int j = 0; j < 2; ++j) bv[j] = bias[n0 + wc * 32 + j * 16 + r16];
  int rbase = m0 + wr * 64 + g4 * 4;
  int cbase = n0 + wc * 32 + r16;
  #pragma unroll
  for (int i = 0; i < 4; ++i)
    #pragma unroll
    for (int rr = 0; rr < 4; ++rr) {
      int m = rbase + i * 16 + rr;
      if (m < Mw) {
        #pragma unroll
        for (int j = 0; j < 2; ++j) {
          float v = acc[i][j][rr] + bv[j];
          if (ACT) v = fmaxf(v, 0.f);
          if (OBF) Cb[(size_t)m * ldc + cbase + j * 16] = f2bf(v);
          else     Cf[(size_t)m * ldc + cbase + j * 16] = v;
        }
      }
    }
}

// ---------------------------------------------------------------------------
// Depth-2 pipelined bf16 MFMA GEMM (fallback path only).
// ---------------------------------------------------------------------------
template <int BM, int BN, int BK, int ACT, int OBF, int NSTRIPE>
__global__ __launch_bounds__(256) void gemm_p2(
    const unsigned short* __restrict__ A, int lda,
    const unsigned short* __restrict__ W, int ldw,
    const float* __restrict__ bias,
    float* __restrict__ Cf, unsigned short* __restrict__ Cb, int ldc,
    int Mw, int K) {
  constexpr int WROWS = BM / 2, WCOLS = BN / 2;
  constexpr int WM = WROWS / 16, WN = WCOLS / 16;
  constexpr int LPR = BK / 8;
  constexpr int RPI = 64 / LPR;
  constexpr int ACH = (BM / 4) / RPI;
  constexpr int BCH = (BN / 4) / RPI;
  constexpr int ABUF = BM * BK, BBUF = BN * BK;
  constexpr int KSUB = BK / 32;
  constexpr int LW = ACH + BCH;
  __shared__ unsigned short lds[3 * (ABUF + BBUF)];

  int tid = threadIdx.x, lane = tid & 63, wid = tid >> 6;
  int gx = gridDim.x;
  int nwg = gx * gridDim.y;
  int orig = blockIdx.y * gx + blockIdx.x;
  int m0, n0;
  if (NSTRIPE && (gx & 7) == 0) {
    int stripe = gx >> 3;
    int xcd = orig & 7, loc = orig >> 3;
    n0 = (xcd * stripe + loc % stripe) * BN;
    m0 = (loc / stripe) * BM;
  } else {
    int q = nwg >> 3, r = nwg & 7;
    int xcd = orig & 7, loc = orig >> 3;
    int wg = (xcd < r ? xcd * (q + 1) : r * (q + 1) + (xcd - r) * q) + loc;
    m0 = (wg / gx) * BM;
    n0 = (wg % gx) * BN;
  }

  int wr = wid >> 1, wc = wid & 1;
  int lrow = lane / LPR, lgrp = lane % LPR;
  int skey = (BK == 32) ? ((lrow >> 1) & 3) : (lrow & 7);
  int lk = (lgrp ^ skey) * 8;

  const unsigned short* gAp[ACH]; unsigned aoff[ACH];
  const unsigned short* gBp[BCH]; unsigned boff[BCH];
  #pragma unroll
  for (int c = 0; c < ACH; ++c) {
    int row0 = wid * (BM / 4) + c * RPI;
    gAp[c] = A + (size_t)(m0 + row0 + lrow) * lda + lk;
    aoff[c] = row0 * BK;
  }
  #pragma unroll
  for (int c = 0; c < BCH; ++c) {
    int row0 = wid * (BN / 4) + c * RPI;
    gBp[c] = W + (size_t)(n0 + row0 + lrow) * ldw + lk;
    boff[c] = row0 * BK;
  }

  f32x4 acc[WM][WN];
  #pragma unroll
  for (int i = 0; i < WM; ++i)
    #pragma unroll
    for (int j = 0; j < WN; ++j) acc[i][j] = (f32x4)0.f;

  int frow = lane & 15, g4 = lane >> 4;

  auto STAGE = [&](int bi, int t) {
    int k0 = t * BK;
    #pragma unroll
    for (int c = 0; c < ACH; ++c)
      __builtin_amdgcn_global_load_lds((gv_t*)(gAp[c] + k0),
          (lv_t*)&lds[bi * ABUF + aoff[c]], 16, 0, 0);
    #pragma unroll
    for (int c = 0; c < BCH; ++c)
      __builtin_amdgcn_global_load_lds((gv_t*)(gBp[c] + k0),
          (lv_t*)&lds[3 * ABUF + bi * BBUF + boff[c]], 16, 0, 0);
  };

  STAGE(0, 0);
  STAGE(1, 1);
  int nt = K / BK;
  int cur = 0;
  for (int t = 0; t < nt; ++t) {
    if (t + 1 < nt) vmwait<LW>(); else vmwait<0>();
    __builtin_amdgcn_s_barrier();
    if (t + 2 < nt) {
      int stb = cur + 2; if (stb >= 3) stb -= 3;
      STAGE(stb, t + 2);
    }
    const unsigned short* Ab = &lds[cur * ABUF];
    const unsigned short* Bb = &lds[3 * ABUF + cur * BBUF];
    #pragma unroll
    for (int kk = 0; kk < KSUB; ++kk) {
      int rk = (BK == 32) ? ((g4 ^ ((frow >> 1) & 3)) * 8)
                          : (((kk * 4 + g4) ^ (frow & 7)) * 8);
      s16x8 af[WM], bfr[WN];
      #pragma unroll
      for (int i = 0; i < WM; ++i)
        af[i] = *(const s16x8*)&Ab[(wr * WROWS + i * 16 + frow) * BK + rk];
      #pragma unroll
      for (int j = 0; j < WN; ++j)
        bfr[j] = *(const s16x8*)&Bb[(wc * WCOLS + j * 16 + frow) * BK + rk];
      __builtin_amdgcn_s_setprio(1);
      #pragma unroll
      for (int i = 0; i < WM; ++i)
        #pragma unroll
        for (int j = 0; j < WN; ++j)
          acc[i][j] = __builtin_amdgcn_mfma_f32_16x16x32_bf16(af[i], bfr[j], acc[i][j], 0, 0, 0);
      __builtin_amdgcn_s_setprio(0);
    }
    cur = (cur == 2) ? 0 : cur + 1;
  }

  float bv[WN];
  #pragma unroll
  for (int j = 0; j < WN; ++j) bv[j] = bias[n0 + wc * WCOLS + j * 16 + (lane & 15)];
  int rbase = m0 + wr * WROWS + (lane >> 4) * 4;
  int cbase = n0 + wc * WCOLS + (lane & 15);
  #pragma unroll
  for (int i = 0; i < WM; ++i)
    #pragma unroll
    for (int rr = 0; rr < 4; ++rr) {
      int m = rbase + i * 16 + rr;
      if (m < Mw) {
        #pragma unroll
        for (int j = 0; j < WN; ++j) {
          float v = acc[i][j][rr] + bv[j];
          if (ACT) v = fmaxf(v, 0.f);
          if (OBF) Cb[(size_t)m * ldc + cbase + j * 16] = f2bf(v);
          else     Cf[(size_t)m * ldc + cbase + j * 16] = v;
        }
      }
    }
}

// ---------------------------------------------------------------------------
// MFMA flash attention, KVBLK=128: 7 K/V-tiles, 32 MFMA per tile between the
// same 2-barrier structure (halves barrier + softmax-reduction overhead).
// K staged via gload_lds with XOR-swizzled source; V reg-staged transposed
// into Vt[d][key] (pad 136); P via per-wave swizzled LDS (16 groups).
// ---------------------------------------------------------------------------
template <bool MASKED>
__global__ __launch_bounds__(256) void attn_mfma(
    const unsigned short* __restrict__ qp, int qld,
    const unsigned short* __restrict__ kp,
    const unsigned short* __restrict__ vp, int kvld,
    unsigned short* __restrict__ out) {
  __shared__ unsigned short KsL[128 * 64];      // [key][d], swizzled groups
  __shared__ unsigned short VtL[64 * 136];      // [d][key], pad 136
  __shared__ unsigned short PsL[4][16 * 128];   // per-wave P, swizzled
  int tid = threadIdx.x;
  int lane = tid & 63, wid = tid >> 6;
  int b = blockIdx.y >> 4, h = blockIdx.y & 15;
  int q0 = blockIdx.x * 64;
  int r16 = lane & 15, g4 = lane >> 4;

  int qrow = q0 + wid * 16 + r16;
  if (qrow >= T_) qrow = T_ - 1;
  const unsigned short* qbase =
      qp + (size_t)(b * T_ + qrow) * qld + h * 64 + g4 * 8;
  s16x8 qf0 = *(const s16x8*)qbase;
  s16x8 qf1 = *(const s16x8*)(qbase + 32);

  float m_[4], l_[4];
  f32x4 o_[4];
  #pragma unroll
  for (int rg = 0; rg < 4; ++rg) { m_[rg] = -INFINITY; l_[rg] = 0.f; }
  #pragma unroll
  for (int dj = 0; dj < 4; ++dj) o_[dj] = (f32x4)0.f;

  int qmax = q0 + 63;

  for (int t = 0; t < 7; ++t) {           // ceil(865/128) = 7
    int k0 = t * 128;
    if (MASKED && k0 > qmax && k0 >= PREFIX_) break;
    __syncthreads();

    // stage K (128 x 64): wave wid covers keys wid*32..+32, 4 insts
    #pragma unroll
    for (int c = 0; c < 4; ++c) {
      int row = wid * 32 + c * 8 + (lane >> 3);
      int kr = k0 + row; if (kr >= T_) kr = T_ - 1;
      int grp = (lane & 7) ^ (row & 7);
      const unsigned short* src =
          kp + (size_t)(b * T_ + kr) * kvld + h * 64 + grp * 8;
      __builtin_amdgcn_global_load_lds((gv_t*)src,
          (lv_t*)&KsL[(wid * 32 + c * 8) * 64], 16, 0, 0);
    }
    // stage V transposed: keys k0+lane and k0+64+lane, dims wid*16..+16
    {
      int vk0 = k0 + lane;      if (vk0 >= T_) vk0 = T_ - 1;
      int vk1 = k0 + 64 + lane; if (vk1 >= T_) vk1 = T_ - 1;
      const unsigned short* vs0 =
          vp + (size_t)(b * T_ + vk0) * kvld + h * 64 + wid * 16;
      const unsigned short* vs1 =
          vp + (size_t)(b * T_ + vk1) * kvld + h * 64 + wid * 16;
      u16x8 a0 = *(const u16x8*)vs0, a1 = *(const u16x8*)(vs0 + 8);
      u16x8 b0 = *(const u16x8*)vs1, b1 = *(const u16x8*)(vs1 + 8);
      #pragma unroll
      for (int jj = 0; jj < 8; ++jj) {
        VtL[(wid * 16 + jj) * 136 + lane]          = a0[jj];
        VtL[(wid * 16 + 8 + jj) * 136 + lane]      = a1[jj];
        VtL[(wid * 16 + jj) * 136 + 64 + lane]     = b0[jj];
        VtL[(wid * 16 + 8 + jj) * 136 + 64 + lane] = b1[jj];
      }
    }
    __syncthreads();

    // --- S = Q K^T : 16 MFMAs ---
    f32x4 sj[8];
    #pragma unroll
    for (int j = 0; j < 8; ++j) sj[j] = (f32x4)0.f;
    __builtin_amdgcn_s_setprio(1);
    #pragma unroll
    for (int j = 0; j < 8; ++j) {
      int krow = j * 16 + r16;
      s16x8 kf0 = *(const s16x8*)&KsL[krow * 64 + ((g4 ^ (krow & 7)) * 8)];
      s16x8 kf1 = *(const s16x8*)&KsL[krow * 64 + (((4 + g4) ^ (krow & 7)) * 8)];
      sj[j] = __builtin_amdgcn_mfma_f32_16x16x32_bf16(qf0, kf0, sj[j], 0, 0, 0);
      sj[j] = __builtin_amdgcn_mfma_f32_16x16x32_bf16(qf1, kf1, sj[j], 0, 0, 0);
    }
    __builtin_amdgcn_s_setprio(0);

    // --- online softmax (rows: q = q0 + wid*16 + g4*4 + reg) ---
    float alpha_[4];
    #pragma unroll
    for (int rg = 0; rg < 4; ++rg) {
      int qa = q0 + wid * 16 + g4 * 4 + rg;
      float pm = -INFINITY;
      #pragma unroll
      for (int j = 0; j < 8; ++j) {
        int kg = k0 + j * 16 + r16;
        float sv = sj[j][rg] * 0.125f;
        bool bad = (kg >= T_) || (MASKED && kg > qa && kg >= PREFIX_);
        sv = bad ? -INFINITY : sv;
        sj[j][rg] = sv;
        pm = fmaxf(pm, sv);
      }
      pm = fmaxf(pm, __shfl_xor(pm, 1));
      pm = fmaxf(pm, __shfl_xor(pm, 2));
      pm = fmaxf(pm, __shfl_xor(pm, 4));
      pm = fmaxf(pm, __shfl_xor(pm, 8));
      float mn = fmaxf(m_[rg], pm);
      float al = __expf(m_[rg] - mn);
      m_[rg] = mn;
      alpha_[rg] = al;
      int prow = g4 * 4 + rg;
      float ps = 0.f;
      #pragma unroll
      for (int j = 0; j < 8; ++j) {
        float pv = __expf(sj[j][rg] - mn);
        ps += pv;
        int grp = (j * 2 + (r16 >> 3)) ^ (prow & 7);
        PsL[wid][prow * 128 + grp * 8 + (r16 & 7)] = f2bf(pv);
      }
      ps += __shfl_xor(ps, 1);
      ps += __shfl_xor(ps, 2);
      ps += __shfl_xor(ps, 4);
      ps += __shfl_xor(ps, 8);
      l_[rg] = l_[rg] * al + ps;
    }
    #pragma unroll
    for (int dj = 0; dj < 4; ++dj)
      #pragma unroll
      for (int rg = 0; rg < 4; ++rg) o_[dj][rg] *= alpha_[rg];

    // --- O += P @ V : 16 MFMAs ---
    __builtin_amdgcn_s_setprio(1);
    #pragma unroll
    for (int kk = 0; kk < 4; ++kk) {
      s16x8 pf = *(const s16x8*)
          &PsL[wid][r16 * 128 + (((kk * 4 + g4) ^ (r16 & 7)) * 8)];
      #pragma unroll
      for (int dj = 0; dj < 4; ++dj) {
        s16x8 vf = *(const s16x8*)
            &VtL[(dj * 16 + r16) * 136 + kk * 32 + g4 * 8];
        o_[dj] = __builtin_amdgcn_mfma_f32_16x16x32_bf16(pf, vf, o_[dj], 0, 0, 0);
      }
    }
    __builtin_amdgcn_s_setprio(0);
  }

  #pragma unroll
  for (int rg = 0; rg < 4; ++rg) {
    int qa = q0 + wid * 16 + g4 * 4 + rg;
    if (qa < T_) {
      float inv = 1.f / l_[rg];
      unsigned short* ob = out + (size_t)(b * T_ + qa) * D_ + h * 64;
      #pragma unroll
      for (int dj = 0; dj < 4; ++dj)
        ob[dj * 16 + r16] = f2bf(o_[dj][rg] * inv);
    }
  }
}

// ---------------------------------------------------------------------------
// xb = bf16( LayerNorm(xb + r) * w + b )  — pure-bf16 residual stream.
// ---------------------------------------------------------------------------
__global__ __launch_bounds__(256) void ln_res_kernel(
    unsigned short* __restrict__ xb, const unsigned short* __restrict__ r,
    const float* __restrict__ w, const float* __restrict__ b) {
  __shared__ float red[4];
  int row = blockIdx.x, tid = threadIdx.x;
  size_t off = (size_t)row * D_ + tid * 4;
  ushort4 xv = *(const ushort4*)&xb[off];
  ushort4 rv = *(const ushort4*)&r[off];
  float v0 = bf2f(xv.x) + bf2f(rv.x), v1 = bf2f(xv.y) + bf2f(rv.y);
  float v2 = bf2f(xv.z) + bf2f(rv.z), v3 = bf2f(xv.w) + bf2f(rv.w);

  float s = v0 + v1 + v2 + v3;
  #pragma unroll
  for (int o = 1; o < 64; o <<= 1) s += __shfl_xor(s, o);
  if ((tid & 63) == 0) red[tid >> 6] = s;
  __syncthreads();
  float mu = (red[0] + red[1] + red[2] + red[3]) * (1.f / 1024.f);
  __syncthreads();

  float d0 = v0 - mu, d1 = v1 - mu, d2 = v2 - mu, d3 = v3 - mu;
  float ss = d0 * d0 + d1 * d1 + d2 * d2 + d3 * d3;
  #pragma unroll
  for (int o = 1; o < 64; o <<= 1) ss += __shfl_xor(ss, o);
  if ((tid & 63) == 0) red[tid >> 6] = ss;
  __syncthreads();
  float var = (red[0] + red[1] + red[2] + red[3]) * (1.f / 1024.f);
  float rs = rsqrtf(var + 1e-5f);

  float4 wv = *(const float4*)&w[tid * 4];
  float4 bv = *(const float4*)&b[tid * 4];
  float o0 = d0 * rs * wv.x + bv.x, o1 = d1 * rs * wv.y + bv.y;
  float o2 = d2 * rs * wv.z + bv.z, o3 = d3 * rs * wv.w + bv.w;
  unsigned long long pk = (unsigned long long)f2bf(o0)
      | ((unsigned long long)f2bf(o1) << 16)
      | ((unsigned long long)f2bf(o2) << 32)
      | ((unsigned long long)f2bf(o3) << 48);
  *(unsigned long long*)&xb[off] = pk;
}

extern "C" void kernel_launch(void* const* d_in, const int* in_sizes, int n_in,
                              void* d_out, int out_size, void* d_ws, size_t ws_size,
                              hipStream_t stream) {
  const int* text       = (const int*)d_in[0];
  const int* audio      = (const int*)d_in[1];
  const int* enrolled   = (const int*)d_in[2];
  const int* tl_b       = (const int*)d_in[3];
  const int* al_b       = (const int*)d_in[4];
  const float* text_emb = (const float*)d_in[5];
  const float* audio_emb= (const float*)d_in[6];
  const float* sa_in_w  = (const float*)d_in[7];
  const float* sa_in_b  = (const float*)d_in[8];
  const float* sa_out_w = (const float*)d_in[9];
  const float* sa_out_b = (const float*)d_in[10];
  const float* ca_in_w  = (const float*)d_in[11];
  const float* ca_in_b  = (const float*)d_in[12];
  const float* ca_out_w = (const float*)d_in[13];
  const float* ca_out_b = (const float*)d_in[14];
  const float* ff1_w    = (const float*)d_in[15];
  const float* ff1_b    = (const float*)d_in[16];
  const float* ff2_w    = (const float*)d_in[17];
  const float* ff2_b    = (const float*)d_in[18];
  const float* ln1_w    = (const float*)d_in[19];
  const float* ln1_b    = (const float*)d_in[20];
  const float* ln2_w    = (const float*)d_in[21];
  const float* ln2_b    = (const float*)d_in[22];
  const float* ln3_w    = (const float*)d_in[23];
  const float* ln3_b    = (const float*)d_in[24];
  const float* out_w    = (const float*)d_in[25];
  const float* out_b    = (const float*)d_in[26];

  char* p = (char*)d_ws;
  unsigned short* tmpb = (unsigned short*)p;  p += (size_t)M_PAD * D_ * 2;
  unsigned short* xb = (unsigned short*)p;    p += (size_t)M_PAD * D_ * 2;
  unsigned short* memb = (unsigned short*)p;  p += (size_t)M_PAD * D_ * 2;
  unsigned short* qkv = (unsigned short*)p;   p += (size_t)M_PAD * FF_ * 2;
  unsigned short* attnb = (unsigned short*)p; p += (size_t)M_PAD * D_ * 2;
  unsigned short* wbuf = (unsigned short*)p;  p += (size_t)16777216 * 2;
  unsigned short* outwb = (unsigned short*)p; p += (size_t)1048576 * 2;
  unsigned short* ckv  = (unsigned short*)p;  p += (size_t)M_PAD * NKV * 2;
  unsigned short* wckv = (unsigned short*)p;  p += (size_t)NKV * D_ * 2;
  float* cbias = (float*)p;                   p += (size_t)NKV * 4;
  bool fused = ((size_t)(p - (char*)d_ws)) <= ws_size;

  unsigned short* w_sa_qkv = wbuf;
  unsigned short* w_sa_o   = wbuf + 3145728;
  unsigned short* w_ca_qkv = wbuf + 4194304;
  unsigned short* w_ca_o   = wbuf + 7340032;
  unsigned short* w_ff1    = wbuf + 8388608;
  unsigned short* w_ff2    = wbuf + 12582912;

  embed_kernel<<<M_PAD, 256, 0, stream>>>(text, audio, enrolled, tl_b, al_b,
                                          text_emb, audio_emb, xb, memb, attnb);
  cvt_kernel<<<512, 256, 0, stream>>>(out_w, outwb, 131072);

  if (fused) {
    cvt_ckv_w<<<NKV, 256, 0, stream>>>(ca_in_w, wckv);
    cvt_ckv_b<<<NKV / 256, 256, 0, stream>>>(ca_in_b, cbias);
    gemm_8w<0, 1, 1><<<dim3(NKV / 256, M_PAD / 256), 512, 0, stream>>>(
        memb, D_, wckv, D_, cbias, nullptr, ckv, NKV, M_PAD, D_);
  }

  for (int l = 0; l < L_; ++l) {
    const float* sa_in_w_l  = sa_in_w  + (size_t)l * 3 * D_ * D_;
    const float* sa_in_b_l  = sa_in_b  + (size_t)l * 3 * D_;
    const float* sa_out_w_l = sa_out_w + (size_t)l * D_ * D_;
    const float* sa_out_b_l = sa_out_b + (size_t)l * D_;
    const float* ca_in_w_l  = ca_in_w  + (size_t)l * 3 * D_ * D_;
    const float* ca_in_b_l  = ca_in_b  + (size_t)l * 3 * D_;
    const float* ca_out_w_l = ca_out_w + (size_t)l * D_ * D_;
    const float* ca_out_b_l = ca_out_b + (size_t)l * D_;
    const float* ff1_w_l    = ff1_w    + (size_t)l * FF_ * D_;
    const float* ff1_b_l    = ff1_b    + (size_t)l * FF_;
    const float* ff2_w_l    = ff2_w    + (size_t)l * D_ * FF_;
    const float* ff2_b_l    = ff2_b    + (size_t)l * D_;

    cvt_layer_kernel<<<8192, 256, 0, stream>>>(sa_in_w_l, sa_out_w_l, ca_in_w_l,
                                               ca_out_w_l, ff1_w_l, ff2_w_l, wbuf);

    // ---- self attention ----
    gemm_8w<0, 1, 1><<<dim3(3 * D_ / 256, M_PAD / 256), 512, 0, stream>>>(
        xb, D_, w_sa_qkv, D_, sa_in_b_l, nullptr, qkv, 3 * D_, M_PAD, D_);
    attn_mfma<true><<<dim3(14, B_ * H_), 256, 0, stream>>>(
        qkv, 3 * D_, qkv + D_, qkv + 2 * D_, 3 * D_, attnb);
    gemm_8w128<0, 1, 0><<<dim3(D_ / 128, M_PAD / 128), 512, 0, stream>>>(
        attnb, D_, w_sa_o, D_, sa_out_b_l, nullptr, tmpb, D_, M_PAD, D_);
    ln_res_kernel<<<M_TOK, 256, 0, stream>>>(xb, tmpb, ln1_w + l * D_, ln1_b + l * D_);

    // ---- cross attention ----
    gemm_8w128<0, 1, 0><<<dim3(D_ / 128, M_PAD / 128), 512, 0, stream>>>(
        xb, D_, w_ca_qkv, D_, ca_in_b_l, nullptr, qkv, 3 * D_, M_PAD, D_);   // q
    if (fused) {
      attn_mfma<false><<<dim3(14, B_ * H_), 256, 0, stream>>>(
          qkv, 3 * D_, ckv + (size_t)l * 2 * D_, ckv + (size_t)l * 2 * D_ + D_,
          NKV, attnb);
    } else {
      gemm_p2<64, 64, 64, 0, 1, 0><<<dim3(2 * D_ / 64, M_PAD / 64), 256, 0, stream>>>(
          memb, D_, w_ca_qkv + (size_t)D_ * D_, D_, ca_in_b_l + D_,
          nullptr, qkv + D_, 3 * D_, M_PAD, D_);
      attn_mfma<false><<<dim3(14, B_ * H_), 256, 0, stream>>>(
          qkv, 3 * D_, qkv + D_, qkv + 2 * D_, 3 * D_, attnb);
    }
    gemm_8w128<0, 1, 0><<<dim3(D_ / 128, M_PAD / 128), 512, 0, stream>>>(
        attnb, D_, w_ca_o, D_, ca_out_b_l, nullptr, tmpb, D_, M_PAD, D_);
    ln_res_kernel<<<M_TOK, 256, 0, stream>>>(xb, tmpb, ln2_w + l * D_, ln2_b + l * D_);

    // ---- feed forward ----
    gemm_8w<1, 1, 1><<<dim3(FF_ / 256, M_PAD / 256), 512, 0, stream>>>(
        xb, D_, w_ff1, D_, ff1_b_l, nullptr, qkv, FF_, M_PAD, D_);
    gemm_8w128<0, 1, 1><<<dim3(D_ / 128, M_PAD / 128), 512, 0, stream>>>(
        qkv, FF_, w_ff2, FF_, ff2_b_l, nullptr, tmpb, D_, M_PAD, FF_);
    ln_res_kernel<<<M_TOK, 256, 0, stream>>>(xb, tmpb, ln3_w + l * D_, ln3_b + l * D_);
  }

  // final projection -> d_out (fp32), only real rows
  gemm_8w128<0, 0, 0><<<dim3(D_ / 128, M_PAD / 128), 512, 0, stream>>>(
      xb, D_, outwb, D_, out_b, (float*)d_out, nullptr, D_, M_TOK, D_);
}

// Round 14
// 1909.208 us; speedup vs baseline: 1.0480x; 1.0480x over previous
//
#include <hip/hip_runtime.h>
#include <hip/hip_bf16.h>

#define B_      4
#define TT_     128
#define TA_     512
#define TE_     225
#define T_      865
#define D_      1024
#define H_      16
#define FF_     4096
#define L_      6
#define PREFIX_ 640
#define M_TOK   (B_ * T_)   // 3460
#define M_PAD   3584        // 28 * 128
#define NKV     (L_ * 2 * D_)   // 12288 concat cross K/V rows

typedef __attribute__((ext_vector_type(8))) short          s16x8;
typedef __attribute__((ext_vector_type(4))) float          f32x4;
typedef __attribute__((ext_vector_type(8))) unsigned short u16x8;

typedef __attribute__((address_space(1))) const void gv_t;
typedef __attribute__((address_space(3))) void       lv_t;

__device__ __forceinline__ float bf2f(unsigned short u) {
  union { unsigned int i; float f; } c; c.i = ((unsigned int)u) << 16; return c.f;
}
__device__ __forceinline__ unsigned short f2bf(float f) {
  union { __hip_bfloat16 h; unsigned short u; } c; c.h = __float2bfloat16(f); return c.u;
}
template <int N> __device__ __forceinline__ void vmwait() {
  asm volatile("s_waitcnt vmcnt(%0)" :: "n"(N) : "memory");
}

// ---------------------------------------------------------------------------
// Embedding + pack + PE. Grid = M_PAD rows; padded rows zero the bf16 bufs.
// ---------------------------------------------------------------------------
__global__ __launch_bounds__(256) void embed_kernel(
    const int* __restrict__ text, const int* __restrict__ audio,
    const int* __restrict__ enrolled, const int* __restrict__ tl_b,
    const int* __restrict__ al_b, const float* __restrict__ text_emb,
    const float* __restrict__ audio_emb,
    unsigned short* __restrict__ xb,
    unsigned short* __restrict__ memb, unsigned short* __restrict__ attnb) {
  int row = blockIdx.x;
  int d0 = threadIdx.x * 4;
  size_t off = (size_t)row * D_ + d0;
  if (row >= M_TOK) {
    *(unsigned long long*)&xb[off]    = 0ull;
    *(unsigned long long*)&memb[off]  = 0ull;
    *(unsigned long long*)&attnb[off] = 0ull;
    return;
  }
  int b = row / T_, pos = row - b * T_;
  int tl = tl_b[b], al = al_b[b];
  const float* emb = nullptr;
  int p = 0;
  if (pos < tl) {
    emb = text_emb + (size_t)text[b * TT_ + pos] * D_;
    p = pos;
  } else if (pos < tl + al) {
    emb = audio_emb + (size_t)audio[b * TA_ + (pos - tl)] * D_;
    p = pos - tl;
  } else if (pos < tl + al + TE_) {
    emb = audio_emb + (size_t)enrolled[b * TE_ + (pos - tl - al)] * D_;
    p = pos - tl - al;
  }
  float4 v;
  float* pv = (float*)&v;
  if (emb) {
    const float c = -9.2103403719761836f / (float)D_;  // -ln(10000)/D
    #pragma unroll
    for (int e = 0; e < 4; ++e) {
      int d = d0 + e;
      int i = d >> 1;
      float freq = expf(c * (float)(2 * i));
      float arg = (float)p * freq;
      float pe = (d & 1) ? cosf(arg) : sinf(arg);
      pv[e] = emb[d] + pe;
    }
  } else {
    v = make_float4(0.f, 0.f, 0.f, 0.f);
  }
  unsigned long long pk = (unsigned long long)f2bf(pv[0])
      | ((unsigned long long)f2bf(pv[1]) << 16)
      | ((unsigned long long)f2bf(pv[2]) << 32)
      | ((unsigned long long)f2bf(pv[3]) << 48);
  *(unsigned long long*)&xb[off]   = pk;
  *(unsigned long long*)&memb[off] = pk;
}

// ---------------------------------------------------------------------------
// fp32 -> bf16 converters.
// ---------------------------------------------------------------------------
__global__ __launch_bounds__(256) void cvt_kernel(
    const float* __restrict__ in, unsigned short* __restrict__ out, int n8) {
  int i = blockIdx.x * 256 + threadIdx.x;
  if (i >= n8) return;
  const float4* pp = (const float4*)in + (size_t)i * 2;
  float4 a = pp[0], bq = pp[1];
  u16x8 o;
  o[0] = f2bf(a.x);  o[1] = f2bf(a.y);  o[2] = f2bf(a.z);  o[3] = f2bf(a.w);
  o[4] = f2bf(bq.x); o[5] = f2bf(bq.y); o[6] = f2bf(bq.z); o[7] = f2bf(bq.w);
  *(u16x8*)(out + (size_t)i * 8) = o;
}

__global__ __launch_bounds__(256) void cvt_layer_kernel(
    const float* __restrict__ s0, const float* __restrict__ s1,
    const float* __restrict__ s2, const float* __restrict__ s3,
    const float* __restrict__ s4, const float* __restrict__ s5,
    unsigned short* __restrict__ dst) {
  size_t e = ((size_t)blockIdx.x * 256 + threadIdx.x) * 8;
  if (e >= 16777216u) return;
  const float* src; size_t off;
  if      (e <  3145728u) { src = s0; off = e; }
  else if (e <  4194304u) { src = s1; off = e -  3145728u; }
  else if (e <  7340032u) { src = s2; off = e -  4194304u; }
  else if (e <  8388608u) { src = s3; off = e -  7340032u; }
  else if (e < 12582912u) { src = s4; off = e -  8388608u; }
  else                    { src = s5; off = e - 12582912u; }
  const float4* pp = (const float4*)(src + off);
  float4 a = pp[0], bq = pp[1];
  u16x8 o;
  o[0] = f2bf(a.x);  o[1] = f2bf(a.y);  o[2] = f2bf(a.z);  o[3] = f2bf(a.w);
  o[4] = f2bf(bq.x); o[5] = f2bf(bq.y); o[6] = f2bf(bq.z); o[7] = f2bf(bq.w);
  *(u16x8*)(dst + e) = o;
}

// Gather all 6 layers' cross-attn K,V weight rows -> wckv (NKV x D).
__global__ __launch_bounds__(256) void cvt_ckv_w(
    const float* __restrict__ ca_in_w, unsigned short* __restrict__ wckv) {
  int rr = blockIdx.x;            // 0..NKV-1
  int l = rr / (2 * D_), w = rr % (2 * D_);   // D_+w spans k then v rows
  const float* src = ca_in_w + (size_t)l * 3 * D_ * D_ + (size_t)(D_ + w) * D_;
  unsigned short* dst = wckv + (size_t)rr * D_;
  int c = threadIdx.x * 4;
  float4 v4 = *(const float4*)(src + c);
  unsigned long long pk = (unsigned long long)f2bf(v4.x)
      | ((unsigned long long)f2bf(v4.y) << 16)
      | ((unsigned long long)f2bf(v4.z) << 32)
      | ((unsigned long long)f2bf(v4.w) << 48);
  *(unsigned long long*)&dst[c] = pk;
}

__global__ __launch_bounds__(256) void cvt_ckv_b(
    const float* __restrict__ ca_in_b, float* __restrict__ cbias) {
  int rr = blockIdx.x * 256 + threadIdx.x;
  if (rr >= NKV) return;
  int l = rr / (2 * D_), w = rr % (2 * D_);
  cbias[rr] = ca_in_b[(size_t)l * 3 * D_ + D_ + w];
}

// ---------------------------------------------------------------------------
// 8-wave fat-tile bf16 MFMA GEMM (round-7 proven schedule): 256x256, BK=64.
// ---------------------------------------------------------------------------
template <int ACT, int OBF, int NSTRIPE>
__global__ __launch_bounds__(512, 2) void gemm_8w(
    const unsigned short* __restrict__ A, int lda,
    const unsigned short* __restrict__ W, int ldw,
    const float* __restrict__ bias,
    float* __restrict__ Cf, unsigned short* __restrict__ Cb, int ldc,
    int Mw, int K) {
  __shared__ unsigned short lds[2][2][256 * 64];   // [buf][A|B][row*64+k]
  int tid = threadIdx.x, lane = tid & 63, wid = tid >> 6;

  int gx = gridDim.x;
  int nwg = gx * gridDim.y;
  int orig = blockIdx.y * gx + blockIdx.x;
  int m0, n0;
  if (NSTRIPE && (gx & 7) == 0) {
    int stripe = gx >> 3;
    int xcd = orig & 7, loc = orig >> 3;
    n0 = (xcd * stripe + loc % stripe) * 256;
    m0 = (loc / stripe) * 256;
  } else {
    int q = nwg >> 3, r = nwg & 7;
    int xcd = orig & 7, loc = orig >> 3;
    int wg = (xcd < r ? xcd * (q + 1) : r * (q + 1) + (xcd - r) * q) + loc;
    m0 = (wg / gx) * 256;
    n0 = (wg % gx) * 256;
  }

  int wr = wid >> 2, wc = wid & 3;         // 2 x 4 wave grid
  int r16 = lane & 15, g4 = lane >> 4;

  int srow = lane >> 3;                    // 0..7 within one inst
  int sgrp = (lane & 7) ^ srow;            // inverse-swizzled k-group
  const unsigned short* gA[4];
  const unsigned short* gB[4];
  unsigned soff[4];
  #pragma unroll
  for (int c = 0; c < 4; ++c) {
    int rb = wid * 32 + c * 8;
    gA[c] = A + (size_t)(m0 + rb + srow) * lda + sgrp * 8;
    gB[c] = W + (size_t)(n0 + rb + srow) * ldw + sgrp * 8;
    soff[c] = rb * 64;
  }

  f32x4 acc[8][4];
  #pragma unroll
  for (int i = 0; i < 8; ++i)
    #pragma unroll
    for (int j = 0; j < 4; ++j) acc[i][j] = (f32x4)0.f;

  auto STAGE = [&](int bi, int t) {
    int k0 = t * 64;
    #pragma unroll
    for (int c = 0; c < 4; ++c)
      __builtin_amdgcn_global_load_lds((gv_t*)(gA[c] + k0),
          (lv_t*)&lds[bi][0][soff[c]], 16, 0, 0);
    #pragma unroll
    for (int c = 0; c < 4; ++c)
      __builtin_amdgcn_global_load_lds((gv_t*)(gB[c] + k0),
          (lv_t*)&lds[bi][1][soff[c]], 16, 0, 0);
  };

  STAGE(0, 0);
  int nt = K / 64, cur = 0;
  for (int t = 0; t < nt; ++t) {
    vmwait<0>();                       // tile t landed (issued last iter)
    __builtin_amdgcn_s_barrier();      // everyone past reads of buf cur^1
    if (t + 1 < nt) STAGE(cur ^ 1, t + 1);   // hides under 64 MFMAs below

    const unsigned short* Ab = &lds[cur][0][0];
    const unsigned short* Bb = &lds[cur][1][0];

    s16x8 bf_[4][2];
    #pragma unroll
    for (int j = 0; j < 4; ++j)
      #pragma unroll
      for (int kk = 0; kk < 2; ++kk) {
        int row = wc * 64 + j * 16 + r16;
        bf_[j][kk] = *(const s16x8*)&Bb[row * 64 + (((kk * 4 + g4) ^ (row & 7)) * 8)];
      }

    #pragma unroll
    for (int p = 0; p < 4; ++p) {      // 4 phases x 16 MFMA
      s16x8 af_[2][2];
      #pragma unroll
      for (int ii = 0; ii < 2; ++ii)
        #pragma unroll
        for (int kk = 0; kk < 2; ++kk) {
          int row = wr * 128 + (p * 2 + ii) * 16 + r16;
          af_[ii][kk] = *(const s16x8*)&Ab[row * 64 + (((kk * 4 + g4) ^ (row & 7)) * 8)];
        }
      __builtin_amdgcn_s_setprio(1);
      #pragma unroll
      for (int kk = 0; kk < 2; ++kk)
        #pragma unroll
        for (int ii = 0; ii < 2; ++ii)
          #pragma unroll
          for (int j = 0; j < 4; ++j)
            acc[p * 2 + ii][j] = __builtin_amdgcn_mfma_f32_16x16x32_bf16(
                af_[ii][kk], bf_[j][kk], acc[p * 2 + ii][j], 0, 0, 0);
      __builtin_amdgcn_s_setprio(0);
    }
    cur ^= 1;
  }

  float bv[4];
  #pragma unroll
  for (int j = 0; j < 4; ++j) bv[j] = bias[n0 + wc * 64 + j * 16 + r16];
  int rbase = m0 + wr * 128 + g4 * 4;
  int cbase = n0 + wc * 64 + r16;
  #pragma unroll
  for (int i = 0; i < 8; ++i)
    #pragma unroll
    for (int rr = 0; rr < 4; ++rr) {
      int m = rbase + i * 16 + rr;
      if (m < Mw) {
        #pragma unroll
        for (int j = 0; j < 4; ++j) {
          float v = acc[i][j][rr] + bv[j];
          if (ACT) v = fmaxf(v, 0.f);
          if (OBF) Cb[(size_t)m * ldc + cbase + j * 16] = f2bf(v);
          else     Cf[(size_t)m * ldc + cbase + j * 16] = v;
        }
      }
    }
}

// ---------------------------------------------------------------------------
// 8-wave 128x128 bf16 MFMA GEMM (round-7 schedule). For N<=1024 shapes only.
// ---------------------------------------------------------------------------
template <int ACT, int OBF, int NSTRIPE>
__global__ __launch_bounds__(512, 2) void gemm_8w128(
    const unsigned short* __restrict__ A, int lda,
    const unsigned short* __restrict__ W, int ldw,
    const float* __restrict__ bias,
    float* __restrict__ Cf, unsigned short* __restrict__ Cb, int ldc,
    int Mw, int K) {
  __shared__ unsigned short lds[2][2][128 * 64];   // 64 KB
  int tid = threadIdx.x, lane = tid & 63, wid = tid >> 6;

  int gx = gridDim.x;
  int nwg = gx * gridDim.y;
  int orig = blockIdx.y * gx + blockIdx.x;
  int m0, n0;
  if (NSTRIPE && (gx & 7) == 0) {
    int stripe = gx >> 3;
    int xcd = orig & 7, loc = orig >> 3;
    n0 = (xcd * stripe + loc % stripe) * 128;
    m0 = (loc / stripe) * 128;
  } else {
    int q = nwg >> 3, r = nwg & 7;
    int xcd = orig & 7, loc = orig >> 3;
    int wg = (xcd < r ? xcd * (q + 1) : r * (q + 1) + (xcd - r) * q) + loc;
    m0 = (wg / gx) * 128;
    n0 = (wg % gx) * 128;
  }

  int wr = wid >> 2, wc = wid & 3;         // 2 x 4 wave grid -> 64 x 32 tiles
  int r16 = lane & 15, g4 = lane >> 4;

  int srow = lane >> 3;
  int sgrp = (lane & 7) ^ srow;
  const unsigned short* gA[2];
  const unsigned short* gB[2];
  unsigned soff[2];
  #pragma unroll
  for (int c = 0; c < 2; ++c) {
    int rb = wid * 16 + c * 8;
    gA[c] = A + (size_t)(m0 + rb + srow) * lda + sgrp * 8;
    gB[c] = W + (size_t)(n0 + rb + srow) * ldw + sgrp * 8;
    soff[c] = rb * 64;
  }

  f32x4 acc[4][2];
  #pragma unroll
  for (int i = 0; i < 4; ++i)
    #pragma unroll
    for (int j = 0; j < 2; ++j) acc[i][j] = (f32x4)0.f;

  auto STAGE = [&](int bi, int t) {   // 4 gload_lds per wave
    int k0 = t * 64;
    #pragma unroll
    for (int c = 0; c < 2; ++c)
      __builtin_amdgcn_global_load_lds((gv_t*)(gA[c] + k0),
          (lv_t*)&lds[bi][0][soff[c]], 16, 0, 0);
    #pragma unroll
    for (int c = 0; c < 2; ++c)
      __builtin_amdgcn_global_load_lds((gv_t*)(gB[c] + k0),
          (lv_t*)&lds[bi][1][soff[c]], 16, 0, 0);
  };

  STAGE(0, 0);
  int nt = K / 64, cur = 0;
  for (int t = 0; t < nt; ++t) {
    vmwait<0>();
    __builtin_amdgcn_s_barrier();
    if (t + 1 < nt) STAGE(cur ^ 1, t + 1);

    const unsigned short* Ab = &lds[cur][0][0];
    const unsigned short* Bb = &lds[cur][1][0];

    s16x8 bf_[2][2];
    #pragma unroll
    for (int j = 0; j < 2; ++j)
      #pragma unroll
      for (int kk = 0; kk < 2; ++kk) {
        int row = wc * 32 + j * 16 + r16;
        bf_[j][kk] = *(const s16x8*)&Bb[row * 64 + (((kk * 4 + g4) ^ (row & 7)) * 8)];
      }
    s16x8 af_[4][2];
    #pragma unroll
    for (int ii = 0; ii < 4; ++ii)
      #pragma unroll
      for (int kk = 0; kk < 2; ++kk) {
        int row = wr * 64 + ii * 16 + r16;
        af_[ii][kk] = *(const s16x8*)&Ab[row * 64 + (((kk * 4 + g4) ^ (row & 7)) * 8)];
      }
    __builtin_amdgcn_s_setprio(1);
    #pragma unroll
    for (int kk = 0; kk < 2; ++kk)
      #pragma unroll
      for (int ii = 0; ii < 4; ++ii)
        #pragma unroll
        for (int j = 0; j < 2; ++j)
          acc[ii][j] = __builtin_amdgcn_mfma_f32_16x16x32_bf16(
              af_[ii][kk], bf_[j][kk], acc[ii][j], 0, 0, 0);
    __builtin_amdgcn_s_setprio(0);
    cur ^= 1;
  }

  float bv[2];
  #pragma unroll
  for (int j = 0; j < 2; ++j) bv[j] = bias[n0 + wc * 32 + j * 16 + r16];
  int rbase = m0 + wr * 64 + g4 * 4;
  int cbase = n0 + wc * 32 + r16;
  #pragma unroll
  for (int i = 0; i < 4; ++i)
    #pragma unroll
    for (int rr = 0; rr < 4; ++rr) {
      int m = rbase + i * 16 + rr;
      if (m < Mw) {
        #pragma unroll
        for (int j = 0; j < 2; ++j) {
          float v = acc[i][j][rr] + bv[j];
          if (ACT) v = fmaxf(v, 0.f);
          if (OBF) Cb[(size_t)m * ldc + cbase + j * 16] = f2bf(v);
          else     Cf[(size_t)m * ldc + cbase + j * 16] = v;
        }
      }
    }
}

// ---------------------------------------------------------------------------
// Depth-2 pipelined bf16 MFMA GEMM (fallback path only).
// ---------------------------------------------------------------------------
template <int BM, int BN, int BK, int ACT, int OBF, int NSTRIPE>
__global__ __launch_bounds__(256) void gemm_p2(
    const unsigned short* __restrict__ A, int lda,
    const unsigned short* __restrict__ W, int ldw,
    const float* __restrict__ bias,
    float* __restrict__ Cf, unsigned short* __restrict__ Cb, int ldc,
    int Mw, int K) {
  constexpr int WROWS = BM / 2, WCOLS = BN / 2;
  constexpr int WM = WROWS / 16, WN = WCOLS / 16;
  constexpr int LPR = BK / 8;
  constexpr int RPI = 64 / LPR;
  constexpr int ACH = (BM / 4) / RPI;
  constexpr int BCH = (BN / 4) / RPI;
  constexpr int ABUF = BM * BK, BBUF = BN * BK;
  constexpr int KSUB = BK / 32;
  constexpr int LW = ACH + BCH;
  __shared__ unsigned short lds[3 * (ABUF + BBUF)];

  int tid = threadIdx.x, lane = tid & 63, wid = tid >> 6;
  int gx = gridDim.x;
  int nwg = gx * gridDim.y;
  int orig = blockIdx.y * gx + blockIdx.x;
  int m0, n0;
  if (NSTRIPE && (gx & 7) == 0) {
    int stripe = gx >> 3;
    int xcd = orig & 7, loc = orig >> 3;
    n0 = (xcd * stripe + loc % stripe) * BN;
    m0 = (loc / stripe) * BM;
  } else {
    int q = nwg >> 3, r = nwg & 7;
    int xcd = orig & 7, loc = orig >> 3;
    int wg = (xcd < r ? xcd * (q + 1) : r * (q + 1) + (xcd - r) * q) + loc;
    m0 = (wg / gx) * BM;
    n0 = (wg % gx) * BN;
  }

  int wr = wid >> 1, wc = wid & 1;
  int lrow = lane / LPR, lgrp = lane % LPR;
  int skey = (BK == 32) ? ((lrow >> 1) & 3) : (lrow & 7);
  int lk = (lgrp ^ skey) * 8;

  const unsigned short* gAp[ACH]; unsigned aoff[ACH];
  const unsigned short* gBp[BCH]; unsigned boff[BCH];
  #pragma unroll
  for (int c = 0; c < ACH; ++c) {
    int row0 = wid * (BM / 4) + c * RPI;
    gAp[c] = A + (size_t)(m0 + row0 + lrow) * lda + lk;
    aoff[c] = row0 * BK;
  }
  #pragma unroll
  for (int c = 0; c < BCH; ++c) {
    int row0 = wid * (BN / 4) + c * RPI;
    gBp[c] = W + (size_t)(n0 + row0 + lrow) * ldw + lk;
    boff[c] = row0 * BK;
  }

  f32x4 acc[WM][WN];
  #pragma unroll
  for (int i = 0; i < WM; ++i)
    #pragma unroll
    for (int j = 0; j < WN; ++j) acc[i][j] = (f32x4)0.f;

  int frow = lane & 15, g4 = lane >> 4;

  auto STAGE = [&](int bi, int t) {
    int k0 = t * BK;
    #pragma unroll
    for (int c = 0; c < ACH; ++c)
      __builtin_amdgcn_global_load_lds((gv_t*)(gAp[c] + k0),
          (lv_t*)&lds[bi * ABUF + aoff[c]], 16, 0, 0);
    #pragma unroll
    for (int c = 0; c < BCH; ++c)
      __builtin_amdgcn_global_load_lds((gv_t*)(gBp[c] + k0),
          (lv_t*)&lds[3 * ABUF + bi * BBUF + boff[c]], 16, 0, 0);
  };

  STAGE(0, 0);
  STAGE(1, 1);
  int nt = K / BK;
  int cur = 0;
  for (int t = 0; t < nt; ++t) {
    if (t + 1 < nt) vmwait<LW>(); else vmwait<0>();
    __builtin_amdgcn_s_barrier();
    if (t + 2 < nt) {
      int stb = cur + 2; if (stb >= 3) stb -= 3;
      STAGE(stb, t + 2);
    }
    const unsigned short* Ab = &lds[cur * ABUF];
    const unsigned short* Bb = &lds[3 * ABUF + cur * BBUF];
    #pragma unroll
    for (int kk = 0; kk < KSUB; ++kk) {
      int rk = (BK == 32) ? ((g4 ^ ((frow >> 1) & 3)) * 8)
                          : (((kk * 4 + g4) ^ (frow & 7)) * 8);
      s16x8 af[WM], bfr[WN];
      #pragma unroll
      for (int i = 0; i < WM; ++i)
        af[i] = *(const s16x8*)&Ab[(wr * WROWS + i * 16 + frow) * BK + rk];
      #pragma unroll
      for (int j = 0; j < WN; ++j)
        bfr[j] = *(const s16x8*)&Bb[(wc * WCOLS + j * 16 + frow) * BK + rk];
      __builtin_amdgcn_s_setprio(1);
      #pragma unroll
      for (int i = 0; i < WM; ++i)
        #pragma unroll
        for (int j = 0; j < WN; ++j)
          acc[i][j] = __builtin_amdgcn_mfma_f32_16x16x32_bf16(af[i], bfr[j], acc[i][j], 0, 0, 0);
      __builtin_amdgcn_s_setprio(0);
    }
    cur = (cur == 2) ? 0 : cur + 1;
  }

  float bv[WN];
  #pragma unroll
  for (int j = 0; j < WN; ++j) bv[j] = bias[n0 + wc * WCOLS + j * 16 + (lane & 15)];
  int rbase = m0 + wr * WROWS + (lane >> 4) * 4;
  int cbase = n0 + wc * WCOLS + (lane & 15);
  #pragma unroll
  for (int i = 0; i < WM; ++i)
    #pragma unroll
    for (int rr = 0; rr < 4; ++rr) {
      int m = rbase + i * 16 + rr;
      if (m < Mw) {
        #pragma unroll
        for (int j = 0; j < WN; ++j) {
          float v = acc[i][j][rr] + bv[j];
          if (ACT) v = fmaxf(v, 0.f);
          if (OBF) Cb[(size_t)m * ldc + cbase + j * 16] = f2bf(v);
          else     Cf[(size_t)m * ldc + cbase + j * 16] = v;
        }
      }
    }
}

// ---------------------------------------------------------------------------
// MFMA flash attention: QBLK=128 (8 waves), KVBLK=64 (round-12 inner loop).
// K/V staging shared by 8 waves (1 gload_lds + 1 V-load per wave per tile);
// barrier count per Q-row halves vs QBLK=64. LDS 33 KB.
// ---------------------------------------------------------------------------
template <bool MASKED>
__global__ __launch_bounds__(512, 2) void attn_mfma(
    const unsigned short* __restrict__ qp, int qld,
    const unsigned short* __restrict__ kp,
    const unsigned short* __restrict__ vp, int kvld,
    unsigned short* __restrict__ out) {
  __shared__ unsigned short KsL[64 * 64];      // [key][d], swizzled groups
  __shared__ unsigned short VtL[64 * 72];      // [d][key], pad 72
  __shared__ unsigned short PsL[8][16 * 64];   // per-wave P, swizzled
  int tid = threadIdx.x;
  int lane = tid & 63, wid = tid >> 6;         // 8 waves
  int b = blockIdx.y >> 4, h = blockIdx.y & 15;
  int q0 = blockIdx.x * 128;
  int r16 = lane & 15, g4 = lane >> 4;

  int qrow = q0 + wid * 16 + r16;
  if (qrow >= T_) qrow = T_ - 1;
  const unsigned short* qbase =
      qp + (size_t)(b * T_ + qrow) * qld + h * 64 + g4 * 8;
  s16x8 qf0 = *(const s16x8*)qbase;
  s16x8 qf1 = *(const s16x8*)(qbase + 32);

  float m_[4], l_[4];
  f32x4 o_[4];
  #pragma unroll
  for (int rg = 0; rg < 4; ++rg) { m_[rg] = -INFINITY; l_[rg] = 0.f; }
  #pragma unroll
  for (int dj = 0; dj < 4; ++dj) o_[dj] = (f32x4)0.f;

  int qmax = q0 + 127;

  for (int t = 0; t < 14; ++t) {
    int k0 = t * 64;
    if (MASKED && k0 > qmax && k0 >= PREFIX_) break;
    __syncthreads();

    // stage K: wave wid covers keys wid*8..+8 (one gload_lds)
    {
      int row = wid * 8 + (lane >> 3);
      int kr = k0 + row; if (kr >= T_) kr = T_ - 1;
      int grp = (lane & 7) ^ (row & 7);
      const unsigned short* src =
          kp + (size_t)(b * T_ + kr) * kvld + h * 64 + grp * 8;
      __builtin_amdgcn_global_load_lds((gv_t*)src,
          (lv_t*)&KsL[(wid * 8) * 64], 16, 0, 0);
    }
    // stage V transposed: wave wid owns d-rows wid*8..+8, key = lane
    {
      int vkr = k0 + lane; if (vkr >= T_) vkr = T_ - 1;
      const unsigned short* vsrc =
          vp + (size_t)(b * T_ + vkr) * kvld + h * 64 + wid * 8;
      u16x8 v0 = *(const u16x8*)vsrc;
      #pragma unroll
      for (int jj = 0; jj < 8; ++jj)
        VtL[(wid * 8 + jj) * 72 + lane] = v0[jj];
    }
    __syncthreads();

    // --- S = Q K^T : 8 MFMAs per wave ---
    f32x4 sj[4];
    #pragma unroll
    for (int j = 0; j < 4; ++j) sj[j] = (f32x4)0.f;
    __builtin_amdgcn_s_setprio(1);
    #pragma unroll
    for (int j = 0; j < 4; ++j) {
      int krow = j * 16 + r16;
      s16x8 kf0 = *(const s16x8*)&KsL[krow * 64 + ((g4 ^ (krow & 7)) * 8)];
      s16x8 kf1 = *(const s16x8*)&KsL[krow * 64 + (((4 + g4) ^ (krow & 7)) * 8)];
      sj[j] = __builtin_amdgcn_mfma_f32_16x16x32_bf16(qf0, kf0, sj[j], 0, 0, 0);
      sj[j] = __builtin_amdgcn_mfma_f32_16x16x32_bf16(qf1, kf1, sj[j], 0, 0, 0);
    }
    __builtin_amdgcn_s_setprio(0);

    // --- online softmax (rows: q = q0 + wid*16 + g4*4 + reg) ---
    float alpha_[4];
    #pragma unroll
    for (int rg = 0; rg < 4; ++rg) {
      int qa = q0 + wid * 16 + g4 * 4 + rg;
      float pm = -INFINITY;
      #pragma unroll
      for (int j = 0; j < 4; ++j) {
        int kg = k0 + j * 16 + r16;
        float sv = sj[j][rg] * 0.125f;
        bool bad = (kg >= T_) || (MASKED && kg > qa && kg >= PREFIX_);
        sv = bad ? -INFINITY : sv;
        sj[j][rg] = sv;
        pm = fmaxf(pm, sv);
      }
      pm = fmaxf(pm, __shfl_xor(pm, 1));
      pm = fmaxf(pm, __shfl_xor(pm, 2));
      pm = fmaxf(pm, __shfl_xor(pm, 4));
      pm = fmaxf(pm, __shfl_xor(pm, 8));
      float mn = fmaxf(m_[rg], pm);
      float al = __expf(m_[rg] - mn);
      m_[rg] = mn;
      alpha_[rg] = al;
      int prow = g4 * 4 + rg;
      float ps = 0.f;
      #pragma unroll
      for (int j = 0; j < 4; ++j) {
        float pv = __expf(sj[j][rg] - mn);
        ps += pv;
        PsL[wid][prow * 64 + (((j * 2 + (r16 >> 3)) ^ (prow & 7)) * 8) + (r16 & 7)]
            = f2bf(pv);
      }
      ps += __shfl_xor(ps, 1);
      ps += __shfl_xor(ps, 2);
      ps += __shfl_xor(ps, 4);
      ps += __shfl_xor(ps, 8);
      l_[rg] = l_[rg] * al + ps;
    }
    #pragma unroll
    for (int dj = 0; dj < 4; ++dj)
      #pragma unroll
      for (int rg = 0; rg < 4; ++rg) o_[dj][rg] *= alpha_[rg];

    // --- O += P @ V : 8 MFMAs per wave ---
    __builtin_amdgcn_s_setprio(1);
    #pragma unroll
    for (int kk = 0; kk < 2; ++kk) {
      s16x8 pf = *(const s16x8*)
          &PsL[wid][r16 * 64 + (((kk * 4 + g4) ^ (r16 & 7)) * 8)];
      #pragma unroll
      for (int dj = 0; dj < 4; ++dj) {
        s16x8 vf = *(const s16x8*)
            &VtL[(dj * 16 + r16) * 72 + kk * 32 + g4 * 8];
        o_[dj] = __builtin_amdgcn_mfma_f32_16x16x32_bf16(pf, vf, o_[dj], 0, 0, 0);
      }
    }
    __builtin_amdgcn_s_setprio(0);
  }

  #pragma unroll
  for (int rg = 0; rg < 4; ++rg) {
    int qa = q0 + wid * 16 + g4 * 4 + rg;
    if (qa < T_) {
      float inv = 1.f / l_[rg];
      unsigned short* ob = out + (size_t)(b * T_ + qa) * D_ + h * 64;
      #pragma unroll
      for (int dj = 0; dj < 4; ++dj)
        ob[dj * 16 + r16] = f2bf(o_[dj][rg] * inv);
    }
  }
}

// ---------------------------------------------------------------------------
// xb = bf16( LayerNorm(xb + r) * w + b )  — pure-bf16 residual stream.
// ---------------------------------------------------------------------------
__global__ __launch_bounds__(256) void ln_res_kernel(
    unsigned short* __restrict__ xb, const unsigned short* __restrict__ r,
    const float* __restrict__ w, const float* __restrict__ b) {
  __shared__ float red[4];
  int row = blockIdx.x, tid = threadIdx.x;
  size_t off = (size_t)row * D_ + tid * 4;
  ushort4 xv = *(const ushort4*)&xb[off];
  ushort4 rv = *(const ushort4*)&r[off];
  float v0 = bf2f(xv.x) + bf2f(rv.x), v1 = bf2f(xv.y) + bf2f(rv.y);
  float v2 = bf2f(xv.z) + bf2f(rv.z), v3 = bf2f(xv.w) + bf2f(rv.w);

  float s = v0 + v1 + v2 + v3;
  #pragma unroll
  for (int o = 1; o < 64; o <<= 1) s += __shfl_xor(s, o);
  if ((tid & 63) == 0) red[tid >> 6] = s;
  __syncthreads();
  float mu = (red[0] + red[1] + red[2] + red[3]) * (1.f / 1024.f);
  __syncthreads();

  float d0 = v0 - mu, d1 = v1 - mu, d2 = v2 - mu, d3 = v3 - mu;
  float ss = d0 * d0 + d1 * d1 + d2 * d2 + d3 * d3;
  #pragma unroll
  for (int o = 1; o < 64; o <<= 1) ss += __shfl_xor(ss, o);
  if ((tid & 63) == 0) red[tid >> 6] = ss;
  __syncthreads();
  float var = (red[0] + red[1] + red[2] + red[3]) * (1.f / 1024.f);
  float rs = rsqrtf(var + 1e-5f);

  float4 wv = *(const float4*)&w[tid * 4];
  float4 bv = *(const float4*)&b[tid * 4];
  float o0 = d0 * rs * wv.x + bv.x, o1 = d1 * rs * wv.y + bv.y;
  float o2 = d2 * rs * wv.z + bv.z, o3 = d3 * rs * wv.w + bv.w;
  unsigned long long pk = (unsigned long long)f2bf(o0)
      | ((unsigned long long)f2bf(o1) << 16)
      | ((unsigned long long)f2bf(o2) << 32)
      | ((unsigned long long)f2bf(o3) << 48);
  *(unsigned long long*)&xb[off] = pk;
}

extern "C" void kernel_launch(void* const* d_in, const int* in_sizes, int n_in,
                              void* d_out, int out_size, void* d_ws, size_t ws_size,
                              hipStream_t stream) {
  const int* text       = (const int*)d_in[0];
  const int* audio      = (const int*)d_in[1];
  const int* enrolled   = (const int*)d_in[2];
  const int* tl_b       = (const int*)d_in[3];
  const int* al_b       = (const int*)d_in[4];
  const float* text_emb = (const float*)d_in[5];
  const float* audio_emb= (const float*)d_in[6];
  const float* sa_in_w  = (const float*)d_in[7];
  const float* sa_in_b  = (const float*)d_in[8];
  const float* sa_out_w = (const float*)d_in[9];
  const float* sa_out_b = (const float*)d_in[10];
  const float* ca_in_w  = (const float*)d_in[11];
  const float* ca_in_b  = (const float*)d_in[12];
  const float* ca_out_w = (const float*)d_in[13];
  const float* ca_out_b = (const float*)d_in[14];
  const float* ff1_w    = (const float*)d_in[15];
  const float* ff1_b    = (const float*)d_in[16];
  const float* ff2_w    = (const float*)d_in[17];
  const float* ff2_b    = (const float*)d_in[18];
  const float* ln1_w    = (const float*)d_in[19];
  const float* ln1_b    = (const float*)d_in[20];
  const float* ln2_w    = (const float*)d_in[21];
  const float* ln2_b    = (const float*)d_in[22];
  const float* ln3_w    = (const float*)d_in[23];
  const float* ln3_b    = (const float*)d_in[24];
  const float* out_w    = (const float*)d_in[25];
  const float* out_b    = (const float*)d_in[26];

  char* p = (char*)d_ws;
  unsigned short* tmpb = (unsigned short*)p;  p += (size_t)M_PAD * D_ * 2;
  unsigned short* xb = (unsigned short*)p;    p += (size_t)M_PAD * D_ * 2;
  unsigned short* memb = (unsigned short*)p;  p += (size_t)M_PAD * D_ * 2;
  unsigned short* qkv = (unsigned short*)p;   p += (size_t)M_PAD * FF_ * 2;
  unsigned short* attnb = (unsigned short*)p; p += (size_t)M_PAD * D_ * 2;
  unsigned short* wbuf = (unsigned short*)p;  p += (size_t)16777216 * 2;
  unsigned short* outwb = (unsigned short*)p; p += (size_t)1048576 * 2;
  unsigned short* ckv  = (unsigned short*)p;  p += (size_t)M_PAD * NKV * 2;
  unsigned short* wckv = (unsigned short*)p;  p += (size_t)NKV * D_ * 2;
  float* cbias = (float*)p;                   p += (size_t)NKV * 4;
  bool fused = ((size_t)(p - (char*)d_ws)) <= ws_size;

  unsigned short* w_sa_qkv = wbuf;
  unsigned short* w_sa_o   = wbuf + 3145728;
  unsigned short* w_ca_qkv = wbuf + 4194304;
  unsigned short* w_ca_o   = wbuf + 7340032;
  unsigned short* w_ff1    = wbuf + 8388608;
  unsigned short* w_ff2    = wbuf + 12582912;

  embed_kernel<<<M_PAD, 256, 0, stream>>>(text, audio, enrolled, tl_b, al_b,
                                          text_emb, audio_emb, xb, memb, attnb);
  cvt_kernel<<<512, 256, 0, stream>>>(out_w, outwb, 131072);

  if (fused) {
    cvt_ckv_w<<<NKV, 256, 0, stream>>>(ca_in_w, wckv);
    cvt_ckv_b<<<NKV / 256, 256, 0, stream>>>(ca_in_b, cbias);
    gemm_8w<0, 1, 1><<<dim3(NKV / 256, M_PAD / 256), 512, 0, stream>>>(
        memb, D_, wckv, D_, cbias, nullptr, ckv, NKV, M_PAD, D_);
  }

  for (int l = 0; l < L_; ++l) {
    const float* sa_in_w_l  = sa_in_w  + (size_t)l * 3 * D_ * D_;
    const float* sa_in_b_l  = sa_in_b  + (size_t)l * 3 * D_;
    const float* sa_out_w_l = sa_out_w + (size_t)l * D_ * D_;
    const float* sa_out_b_l = sa_out_b + (size_t)l * D_;
    const float* ca_in_w_l  = ca_in_w  + (size_t)l * 3 * D_ * D_;
    const float* ca_in_b_l  = ca_in_b  + (size_t)l * 3 * D_;
    const float* ca_out_w_l = ca_out_w + (size_t)l * D_ * D_;
    const float* ca_out_b_l = ca_out_b + (size_t)l * D_;
    const float* ff1_w_l    = ff1_w    + (size_t)l * FF_ * D_;
    const float* ff1_b_l    = ff1_b    + (size_t)l * FF_;
    const float* ff2_w_l    = ff2_w    + (size_t)l * D_ * FF_;
    const float* ff2_b_l    = ff2_b    + (size_t)l * D_;

    cvt_layer_kernel<<<8192, 256, 0, stream>>>(sa_in_w_l, sa_out_w_l, ca_in_w_l,
                                               ca_out_w_l, ff1_w_l, ff2_w_l, wbuf);

    // ---- self attention ----
    gemm_8w<0, 1, 1><<<dim3(3 * D_ / 256, M_PAD / 256), 512, 0, stream>>>(
        xb, D_, w_sa_qkv, D_, sa_in_b_l, nullptr, qkv, 3 * D_, M_PAD, D_);
    attn_mfma<true><<<dim3(7, B_ * H_), 512, 0, stream>>>(
        qkv, 3 * D_, qkv + D_, qkv + 2 * D_, 3 * D_, attnb);
    gemm_8w128<0, 1, 0><<<dim3(D_ / 128, M_PAD / 128), 512, 0, stream>>>(
        attnb, D_, w_sa_o, D_, sa_out_b_l, nullptr, tmpb, D_, M_PAD, D_);
    ln_res_kernel<<<M_TOK, 256, 0, stream>>>(xb, tmpb, ln1_w + l * D_, ln1_b + l * D_);

    // ---- cross attention ----
    gemm_8w128<0, 1, 0><<<dim3(D_ / 128, M_PAD / 128), 512, 0, stream>>>(
        xb, D_, w_ca_qkv, D_, ca_in_b_l, nullptr, qkv, 3 * D_, M_PAD, D_);   // q
    if (fused) {
      attn_mfma<false><<<dim3(7, B_ * H_), 512, 0, stream>>>(
          qkv, 3 * D_, ckv + (size_t)l * 2 * D_, ckv + (size_t)l * 2 * D_ + D_,
          NKV, attnb);
    } else {
      gemm_p2<64, 64, 64, 0, 1, 0><<<dim3(2 * D_ / 64, M_PAD / 64), 256, 0, stream>>>(
          memb, D_, w_ca_qkv + (size_t)D_ * D_, D_, ca_in_b_l + D_,
          nullptr, qkv + D_, 3 * D_, M_PAD, D_);
      attn_mfma<false><<<dim3(7, B_ * H_), 512, 0, stream>>>(
          qkv, 3 * D_, qkv + D_, qkv + 2 * D_, 3 * D_, attnb);
    }
    gemm_8w128<0, 1, 0><<<dim3(D_ / 128, M_PAD / 128), 512, 0, stream>>>(
        attnb, D_, w_ca_o, D_, ca_out_b_l, nullptr, tmpb, D_, M_PAD, D_);
    ln_res_kernel<<<M_TOK, 256, 0, stream>>>(xb, tmpb, ln2_w + l * D_, ln2_b + l * D_);

    // ---- feed forward ----
    gemm_8w<1, 1, 1><<<dim3(FF_ / 256, M_PAD / 256), 512, 0, stream>>>(
        xb, D_, w_ff1, D_, ff1_b_l, nullptr, qkv, FF_, M_PAD, D_);
    gemm_8w128<0, 1, 1><<<dim3(D_ / 128, M_PAD / 128), 512, 0, stream>>>(
        qkv, FF_, w_ff2, FF_, ff2_b_l, nullptr, tmpb, D_, M_PAD, FF_);
    ln_res_kernel<<<M_TOK, 256, 0, stream>>>(xb, tmpb, ln3_w + l * D_, ln3_b + l * D_);
  }

  // final projection -> d_out (fp32), only real rows
  gemm_8w128<0, 0, 0><<<dim3(D_ / 128, M_PAD / 128), 512, 0, stream>>>(
      xb, D_, outwb, D_, out_b, (float*)d_out, nullptr, D_, M_TOK, D_);
}

// Round 15
// 1852.704 us; speedup vs baseline: 1.0800x; 1.0305x over previous
//
#include <hip/hip_runtime.h>
#include <hip/hip_bf16.h>

#define B_      4
#define TT_     128
#define TA_     512
#define TE_     225
#define T_      865
#define D_      1024
#define H_      16
#define FF_     4096
#define L_      6
#define PREFIX_ 640
#define M_TOK   (B_ * T_)   // 3460
#define M_PAD   3584        // 28 * 128
#define NKV     (L_ * 2 * D_)   // 12288 concat cross K/V rows

typedef __attribute__((ext_vector_type(8))) short          s16x8;
typedef __attribute__((ext_vector_type(4))) float          f32x4;
typedef __attribute__((ext_vector_type(8))) unsigned short u16x8;

typedef __attribute__((address_space(1))) const void gv_t;
typedef __attribute__((address_space(3))) void       lv_t;

__device__ __forceinline__ float bf2f(unsigned short u) {
  union { unsigned int i; float f; } c; c.i = ((unsigned int)u) << 16; return c.f;
}
__device__ __forceinline__ unsigned short f2bf(float f) {
  union { __hip_bfloat16 h; unsigned short u; } c; c.h = __float2bfloat16(f); return c.u;
}
template <int N> __device__ __forceinline__ void vmwait() {
  asm volatile("s_waitcnt vmcnt(%0)" :: "n"(N) : "memory");
}

// ---------------------------------------------------------------------------
// Embedding + pack + PE. Grid = M_PAD rows; padded rows zero the bf16 bufs.
// ---------------------------------------------------------------------------
__global__ __launch_bounds__(256) void embed_kernel(
    const int* __restrict__ text, const int* __restrict__ audio,
    const int* __restrict__ enrolled, const int* __restrict__ tl_b,
    const int* __restrict__ al_b, const float* __restrict__ text_emb,
    const float* __restrict__ audio_emb,
    unsigned short* __restrict__ xb,
    unsigned short* __restrict__ memb, unsigned short* __restrict__ attnb) {
  int row = blockIdx.x;
  int d0 = threadIdx.x * 4;
  size_t off = (size_t)row * D_ + d0;
  if (row >= M_TOK) {
    *(unsigned long long*)&xb[off]    = 0ull;
    *(unsigned long long*)&memb[off]  = 0ull;
    *(unsigned long long*)&attnb[off] = 0ull;
    return;
  }
  int b = row / T_, pos = row - b * T_;
  int tl = tl_b[b], al = al_b[b];
  const float* emb = nullptr;
  int p = 0;
  if (pos < tl) {
    emb = text_emb + (size_t)text[b * TT_ + pos] * D_;
    p = pos;
  } else if (pos < tl + al) {
    emb = audio_emb + (size_t)audio[b * TA_ + (pos - tl)] * D_;
    p = pos - tl;
  } else if (pos < tl + al + TE_) {
    emb = audio_emb + (size_t)enrolled[b * TE_ + (pos - tl - al)] * D_;
    p = pos - tl - al;
  }
  float4 v;
  float* pv = (float*)&v;
  if (emb) {
    const float c = -9.2103403719761836f / (float)D_;  // -ln(10000)/D
    #pragma unroll
    for (int e = 0; e < 4; ++e) {
      int d = d0 + e;
      int i = d >> 1;
      float freq = expf(c * (float)(2 * i));
      float arg = (float)p * freq;
      float pe = (d & 1) ? cosf(arg) : sinf(arg);
      pv[e] = emb[d] + pe;
    }
  } else {
    v = make_float4(0.f, 0.f, 0.f, 0.f);
  }
  unsigned long long pk = (unsigned long long)f2bf(pv[0])
      | ((unsigned long long)f2bf(pv[1]) << 16)
      | ((unsigned long long)f2bf(pv[2]) << 32)
      | ((unsigned long long)f2bf(pv[3]) << 48);
  *(unsigned long long*)&xb[off]   = pk;
  *(unsigned long long*)&memb[off] = pk;
}

// ---------------------------------------------------------------------------
// fp32 -> bf16 converters.
// ---------------------------------------------------------------------------
__global__ __launch_bounds__(256) void cvt_kernel(
    const float* __restrict__ in, unsigned short* __restrict__ out, int n8) {
  int i = blockIdx.x * 256 + threadIdx.x;
  if (i >= n8) return;
  const float4* pp = (const float4*)in + (size_t)i * 2;
  float4 a = pp[0], bq = pp[1];
  u16x8 o;
  o[0] = f2bf(a.x);  o[1] = f2bf(a.y);  o[2] = f2bf(a.z);  o[3] = f2bf(a.w);
  o[4] = f2bf(bq.x); o[5] = f2bf(bq.y); o[6] = f2bf(bq.z); o[7] = f2bf(bq.w);
  *(u16x8*)(out + (size_t)i * 8) = o;
}

__global__ __launch_bounds__(256) void cvt_layer_kernel(
    const float* __restrict__ s0, const float* __restrict__ s1,
    const float* __restrict__ s2, const float* __restrict__ s3,
    const float* __restrict__ s4, const float* __restrict__ s5,
    unsigned short* __restrict__ dst) {
  size_t e = ((size_t)blockIdx.x * 256 + threadIdx.x) * 8;
  if (e >= 16777216u) return;
  const float* src; size_t off;
  if      (e <  3145728u) { src = s0; off = e; }
  else if (e <  4194304u) { src = s1; off = e -  3145728u; }
  else if (e <  7340032u) { src = s2; off = e -  4194304u; }
  else if (e <  8388608u) { src = s3; off = e -  7340032u; }
  else if (e < 12582912u) { src = s4; off = e -  8388608u; }
  else                    { src = s5; off = e - 12582912u; }
  const float4* pp = (const float4*)(src + off);
  float4 a = pp[0], bq = pp[1];
  u16x8 o;
  o[0] = f2bf(a.x);  o[1] = f2bf(a.y);  o[2] = f2bf(a.z);  o[3] = f2bf(a.w);
  o[4] = f2bf(bq.x); o[5] = f2bf(bq.y); o[6] = f2bf(bq.z); o[7] = f2bf(bq.w);
  *(u16x8*)(dst + e) = o;
}

// Gather all 6 layers' cross-attn K,V weight rows -> wckv (NKV x D).
__global__ __launch_bounds__(256) void cvt_ckv_w(
    const float* __restrict__ ca_in_w, unsigned short* __restrict__ wckv) {
  int rr = blockIdx.x;            // 0..NKV-1
  int l = rr / (2 * D_), w = rr % (2 * D_);   // D_+w spans k then v rows
  const float* src = ca_in_w + (size_t)l * 3 * D_ * D_ + (size_t)(D_ + w) * D_;
  unsigned short* dst = wckv + (size_t)rr * D_;
  int c = threadIdx.x * 4;
  float4 v4 = *(const float4*)(src + c);
  unsigned long long pk = (unsigned long long)f2bf(v4.x)
      | ((unsigned long long)f2bf(v4.y) << 16)
      | ((unsigned long long)f2bf(v4.z) << 32)
      | ((unsigned long long)f2bf(v4.w) << 48);
  *(unsigned long long*)&dst[c] = pk;
}

__global__ __launch_bounds__(256) void cvt_ckv_b(
    const float* __restrict__ ca_in_b, float* __restrict__ cbias) {
  int rr = blockIdx.x * 256 + threadIdx.x;
  if (rr >= NKV) return;
  int l = rr / (2 * D_), w = rr % (2 * D_);
  cbias[rr] = ca_in_b[(size_t)l * 3 * D_ + D_ + w];
}

// ---------------------------------------------------------------------------
// 8-wave fat-tile bf16 MFMA GEMM (round-7 proven schedule): 256x256, BK=64.
// ---------------------------------------------------------------------------
template <int ACT, int OBF, int NSTRIPE>
__global__ __launch_bounds__(512, 2) void gemm_8w(
    const unsigned short* __restrict__ A, int lda,
    const unsigned short* __restrict__ W, int ldw,
    const float* __restrict__ bias,
    float* __restrict__ Cf, unsigned short* __restrict__ Cb, int ldc,
    int Mw, int K) {
  __shared__ unsigned short lds[2][2][256 * 64];   // [buf][A|B][row*64+k]
  int tid = threadIdx.x, lane = tid & 63, wid = tid >> 6;

  int gx = gridDim.x;
  int nwg = gx * gridDim.y;
  int orig = blockIdx.y * gx + blockIdx.x;
  int m0, n0;
  if (NSTRIPE && (gx & 7) == 0) {
    int stripe = gx >> 3;
    int xcd = orig & 7, loc = orig >> 3;
    n0 = (xcd * stripe + loc % stripe) * 256;
    m0 = (loc / stripe) * 256;
  } else {
    int q = nwg >> 3, r = nwg & 7;
    int xcd = orig & 7, loc = orig >> 3;
    int wg = (xcd < r ? xcd * (q + 1) : r * (q + 1) + (xcd - r) * q) + loc;
    m0 = (wg / gx) * 256;
    n0 = (wg % gx) * 256;
  }

  int wr = wid >> 2, wc = wid & 3;         // 2 x 4 wave grid
  int r16 = lane & 15, g4 = lane >> 4;

  int srow = lane >> 3;                    // 0..7 within one inst
  int sgrp = (lane & 7) ^ srow;            // inverse-swizzled k-group
  const unsigned short* gA[4];
  const unsigned short* gB[4];
  unsigned soff[4];
  #pragma unroll
  for (int c = 0; c < 4; ++c) {
    int rb = wid * 32 + c * 8;
    gA[c] = A + (size_t)(m0 + rb + srow) * lda + sgrp * 8;
    gB[c] = W + (size_t)(n0 + rb + srow) * ldw + sgrp * 8;
    soff[c] = rb * 64;
  }

  f32x4 acc[8][4];
  #pragma unroll
  for (int i = 0; i < 8; ++i)
    #pragma unroll
    for (int j = 0; j < 4; ++j) acc[i][j] = (f32x4)0.f;

  auto STAGE = [&](int bi, int t) {
    int k0 = t * 64;
    #pragma unroll
    for (int c = 0; c < 4; ++c)
      __builtin_amdgcn_global_load_lds((gv_t*)(gA[c] + k0),
          (lv_t*)&lds[bi][0][soff[c]], 16, 0, 0);
    #pragma unroll
    for (int c = 0; c < 4; ++c)
      __builtin_amdgcn_global_load_lds((gv_t*)(gB[c] + k0),
          (lv_t*)&lds[bi][1][soff[c]], 16, 0, 0);
  };

  STAGE(0, 0);
  int nt = K / 64, cur = 0;
  for (int t = 0; t < nt; ++t) {
    vmwait<0>();                       // tile t landed (issued last iter)
    __builtin_amdgcn_s_barrier();      // everyone past reads of buf cur^1
    if (t + 1 < nt) STAGE(cur ^ 1, t + 1);   // hides under 64 MFMAs below

    const unsigned short* Ab = &lds[cur][0][0];
    const unsigned short* Bb = &lds[cur][1][0];

    s16x8 bf_[4][2];
    #pragma unroll
    for (int j = 0; j < 4; ++j)
      #pragma unroll
      for (int kk = 0; kk < 2; ++kk) {
        int row = wc * 64 + j * 16 + r16;
        bf_[j][kk] = *(const s16x8*)&Bb[row * 64 + (((kk * 4 + g4) ^ (row & 7)) * 8)];
      }

    #pragma unroll
    for (int p = 0; p < 4; ++p) {      // 4 phases x 16 MFMA
      s16x8 af_[2][2];
      #pragma unroll
      for (int ii = 0; ii < 2; ++ii)
        #pragma unroll
        for (int kk = 0; kk < 2; ++kk) {
          int row = wr * 128 + (p * 2 + ii) * 16 + r16;
          af_[ii][kk] = *(const s16x8*)&Ab[row * 64 + (((kk * 4 + g4) ^ (row & 7)) * 8)];
        }
      __builtin_amdgcn_s_setprio(1);
      #pragma unroll
      for (int kk = 0; kk < 2; ++kk)
        #pragma unroll
        for (int ii = 0; ii < 2; ++ii)
          #pragma unroll
          for (int j = 0; j < 4; ++j)
            acc[p * 2 + ii][j] = __builtin_amdgcn_mfma_f32_16x16x32_bf16(
                af_[ii][kk], bf_[j][kk], acc[p * 2 + ii][j], 0, 0, 0);
      __builtin_amdgcn_s_setprio(0);
    }
    cur ^= 1;
  }

  float bv[4];
  #pragma unroll
  for (int j = 0; j < 4; ++j) bv[j] = bias[n0 + wc * 64 + j * 16 + r16];
  int rbase = m0 + wr * 128 + g4 * 4;
  int cbase = n0 + wc * 64 + r16;
  #pragma unroll
  for (int i = 0; i < 8; ++i)
    #pragma unroll
    for (int rr = 0; rr < 4; ++rr) {
      int m = rbase + i * 16 + rr;
      if (m < Mw) {
        #pragma unroll
        for (int j = 0; j < 4; ++j) {
          float v = acc[i][j][rr] + bv[j];
          if (ACT) v = fmaxf(v, 0.f);
          if (OBF) Cb[(size_t)m * ldc + cbase + j * 16] = f2bf(v);
          else     Cf[(size_t)m * ldc + cbase + j * 16] = v;
        }
      }
    }
}

// ---------------------------------------------------------------------------
// 8-wave 128x128 bf16 MFMA GEMM (round-7 schedule). For N<=1024 shapes.
// SPLITK: gridDim.z=2, block.z selects K-half (A+=z*K, W+=z*K, bias zeroed
// for z=1) and writes partial z at Cb + z*Mw*ldc. Combine folded into LN.
// ---------------------------------------------------------------------------
template <int ACT, int OBF, int NSTRIPE, int SPLITK>
__global__ __launch_bounds__(512, 2) void gemm_8w128(
    const unsigned short* __restrict__ A, int lda,
    const unsigned short* __restrict__ W, int ldw,
    const float* __restrict__ bias,
    float* __restrict__ Cf, unsigned short* __restrict__ Cb, int ldc,
    int Mw, int K) {
  __shared__ unsigned short lds[2][2][128 * 64];   // 64 KB
  int tid = threadIdx.x, lane = tid & 63, wid = tid >> 6;

  int zpart = 0;
  if (SPLITK) {
    zpart = blockIdx.z;
    A += (size_t)zpart * K;            // column offset within rows
    W += (size_t)zpart * K;
    Cb += (size_t)zpart * Mw * ldc;
    Cf += (size_t)zpart * Mw * ldc;
  }

  int gx = gridDim.x;
  int nwg = gx * gridDim.y;
  int orig = blockIdx.y * gx + blockIdx.x;
  int m0, n0;
  if (NSTRIPE && (gx & 7) == 0) {
    int stripe = gx >> 3;
    int xcd = orig & 7, loc = orig >> 3;
    n0 = (xcd * stripe + loc % stripe) * 128;
    m0 = (loc / stripe) * 128;
  } else {
    int q = nwg >> 3, r = nwg & 7;
    int xcd = orig & 7, loc = orig >> 3;
    int wg = (xcd < r ? xcd * (q + 1) : r * (q + 1) + (xcd - r) * q) + loc;
    m0 = (wg / gx) * 128;
    n0 = (wg % gx) * 128;
  }

  int wr = wid >> 2, wc = wid & 3;         // 2 x 4 wave grid -> 64 x 32 tiles
  int r16 = lane & 15, g4 = lane >> 4;

  int srow = lane >> 3;
  int sgrp = (lane & 7) ^ srow;
  const unsigned short* gA[2];
  const unsigned short* gB[2];
  unsigned soff[2];
  #pragma unroll
  for (int c = 0; c < 2; ++c) {
    int rb = wid * 16 + c * 8;
    gA[c] = A + (size_t)(m0 + rb + srow) * lda + sgrp * 8;
    gB[c] = W + (size_t)(n0 + rb + srow) * ldw + sgrp * 8;
    soff[c] = rb * 64;
  }

  f32x4 acc[4][2];
  #pragma unroll
  for (int i = 0; i < 4; ++i)
    #pragma unroll
    for (int j = 0; j < 2; ++j) acc[i][j] = (f32x4)0.f;

  auto STAGE = [&](int bi, int t) {   // 4 gload_lds per wave
    int k0 = t * 64;
    #pragma unroll
    for (int c = 0; c < 2; ++c)
      __builtin_amdgcn_global_load_lds((gv_t*)(gA[c] + k0),
          (lv_t*)&lds[bi][0][soff[c]], 16, 0, 0);
    #pragma unroll
    for (int c = 0; c < 2; ++c)
      __builtin_amdgcn_global_load_lds((gv_t*)(gB[c] + k0),
          (lv_t*)&lds[bi][1][soff[c]], 16, 0, 0);
  };

  STAGE(0, 0);
  int nt = K / 64, cur = 0;
  for (int t = 0; t < nt; ++t) {
    vmwait<0>();
    __builtin_amdgcn_s_barrier();
    if (t + 1 < nt) STAGE(cur ^ 1, t + 1);

    const unsigned short* Ab = &lds[cur][0][0];
    const unsigned short* Bb = &lds[cur][1][0];

    s16x8 bf_[2][2];
    #pragma unroll
    for (int j = 0; j < 2; ++j)
      #pragma unroll
      for (int kk = 0; kk < 2; ++kk) {
        int row = wc * 32 + j * 16 + r16;
        bf_[j][kk] = *(const s16x8*)&Bb[row * 64 + (((kk * 4 + g4) ^ (row & 7)) * 8)];
      }
    s16x8 af_[4][2];
    #pragma unroll
    for (int ii = 0; ii < 4; ++ii)
      #pragma unroll
      for (int kk = 0; kk < 2; ++kk) {
        int row = wr * 64 + ii * 16 + r16;
        af_[ii][kk] = *(const s16x8*)&Ab[row * 64 + (((kk * 4 + g4) ^ (row & 7)) * 8)];
      }
    __builtin_amdgcn_s_setprio(1);
    #pragma unroll
    for (int kk = 0; kk < 2; ++kk)
      #pragma unroll
      for (int ii = 0; ii < 4; ++ii)
        #pragma unroll
        for (int j = 0; j < 2; ++j)
          acc[ii][j] = __builtin_amdgcn_mfma_f32_16x16x32_bf16(
              af_[ii][kk], bf_[j][kk], acc[ii][j], 0, 0, 0);
    __builtin_amdgcn_s_setprio(0);
    cur ^= 1;
  }

  float bv[2];
  #pragma unroll
  for (int j = 0; j < 2; ++j)
    bv[j] = (SPLITK && zpart) ? 0.f : bias[n0 + wc * 32 + j * 16 + r16];
  int rbase = m0 + wr * 64 + g4 * 4;
  int cbase = n0 + wc * 32 + r16;
  #pragma unroll
  for (int i = 0; i < 4; ++i)
    #pragma unroll
    for (int rr = 0; rr < 4; ++rr) {
      int m = rbase + i * 16 + rr;
      if (m < Mw) {
        #pragma unroll
        for (int j = 0; j < 2; ++j) {
          float v = acc[i][j][rr] + bv[j];
          if (ACT) v = fmaxf(v, 0.f);
          if (OBF) Cb[(size_t)m * ldc + cbase + j * 16] = f2bf(v);
          else     Cf[(size_t)m * ldc + cbase + j * 16] = v;
        }
      }
    }
}

// ---------------------------------------------------------------------------
// MFMA flash attention: QBLK=128 (8 waves), KVBLK=64 (proven round-14 version).
// ---------------------------------------------------------------------------
template <bool MASKED>
__global__ __launch_bounds__(512, 2) void attn_mfma(
    const unsigned short* __restrict__ qp, int qld,
    const unsigned short* __restrict__ kp,
    const unsigned short* __restrict__ vp, int kvld,
    unsigned short* __restrict__ out) {
  __shared__ unsigned short KsL[64 * 64];      // [key][d], swizzled groups
  __shared__ unsigned short VtL[64 * 72];      // [d][key], pad 72
  __shared__ unsigned short PsL[8][16 * 64];   // per-wave P, swizzled
  int tid = threadIdx.x;
  int lane = tid & 63, wid = tid >> 6;         // 8 waves
  int b = blockIdx.y >> 4, h = blockIdx.y & 15;
  int q0 = blockIdx.x * 128;
  int r16 = lane & 15, g4 = lane >> 4;

  int qrow = q0 + wid * 16 + r16;
  if (qrow >= T_) qrow = T_ - 1;
  const unsigned short* qbase =
      qp + (size_t)(b * T_ + qrow) * qld + h * 64 + g4 * 8;
  s16x8 qf0 = *(const s16x8*)qbase;
  s16x8 qf1 = *(const s16x8*)(qbase + 32);

  float m_[4], l_[4];
  f32x4 o_[4];
  #pragma unroll
  for (int rg = 0; rg < 4; ++rg) { m_[rg] = -INFINITY; l_[rg] = 0.f; }
  #pragma unroll
  for (int dj = 0; dj < 4; ++dj) o_[dj] = (f32x4)0.f;

  int qmax = q0 + 127;

  for (int t = 0; t < 14; ++t) {
    int k0 = t * 64;
    if (MASKED && k0 > qmax && k0 >= PREFIX_) break;
    __syncthreads();

    {
      int row = wid * 8 + (lane >> 3);
      int kr = k0 + row; if (kr >= T_) kr = T_ - 1;
      int grp = (lane & 7) ^ (row & 7);
      const unsigned short* src =
          kp + (size_t)(b * T_ + kr) * kvld + h * 64 + grp * 8;
      __builtin_amdgcn_global_load_lds((gv_t*)src,
          (lv_t*)&KsL[(wid * 8) * 64], 16, 0, 0);
    }
    {
      int vkr = k0 + lane; if (vkr >= T_) vkr = T_ - 1;
      const unsigned short* vsrc =
          vp + (size_t)(b * T_ + vkr) * kvld + h * 64 + wid * 8;
      u16x8 v0 = *(const u16x8*)vsrc;
      #pragma unroll
      for (int jj = 0; jj < 8; ++jj)
        VtL[(wid * 8 + jj) * 72 + lane] = v0[jj];
    }
    __syncthreads();

    f32x4 sj[4];
    #pragma unroll
    for (int j = 0; j < 4; ++j) sj[j] = (f32x4)0.f;
    __builtin_amdgcn_s_setprio(1);
    #pragma unroll
    for (int j = 0; j < 4; ++j) {
      int krow = j * 16 + r16;
      s16x8 kf0 = *(const s16x8*)&KsL[krow * 64 + ((g4 ^ (krow & 7)) * 8)];
      s16x8 kf1 = *(const s16x8*)&KsL[krow * 64 + (((4 + g4) ^ (krow & 7)) * 8)];
      sj[j] = __builtin_amdgcn_mfma_f32_16x16x32_bf16(qf0, kf0, sj[j], 0, 0, 0);
      sj[j] = __builtin_amdgcn_mfma_f32_16x16x32_bf16(qf1, kf1, sj[j], 0, 0, 0);
    }
    __builtin_amdgcn_s_setprio(0);

    float alpha_[4];
    #pragma unroll
    for (int rg = 0; rg < 4; ++rg) {
      int qa = q0 + wid * 16 + g4 * 4 + rg;
      float pm = -INFINITY;
      #pragma unroll
      for (int j = 0; j < 4; ++j) {
        int kg = k0 + j * 16 + r16;
        float sv = sj[j][rg] * 0.125f;
        bool bad = (kg >= T_) || (MASKED && kg > qa && kg >= PREFIX_);
        sv = bad ? -INFINITY : sv;
        sj[j][rg] = sv;
        pm = fmaxf(pm, sv);
      }
      pm = fmaxf(pm, __shfl_xor(pm, 1));
      pm = fmaxf(pm, __shfl_xor(pm, 2));
      pm = fmaxf(pm, __shfl_xor(pm, 4));
      pm = fmaxf(pm, __shfl_xor(pm, 8));
      float mn = fmaxf(m_[rg], pm);
      float al = __expf(m_[rg] - mn);
      m_[rg] = mn;
      alpha_[rg] = al;
      int prow = g4 * 4 + rg;
      float ps = 0.f;
      #pragma unroll
      for (int j = 0; j < 4; ++j) {
        float pv = __expf(sj[j][rg] - mn);
        ps += pv;
        PsL[wid][prow * 64 + (((j * 2 + (r16 >> 3)) ^ (prow & 7)) * 8) + (r16 & 7)]
            = f2bf(pv);
      }
      ps += __shfl_xor(ps, 1);
      ps += __shfl_xor(ps, 2);
      ps += __shfl_xor(ps, 4);
      ps += __shfl_xor(ps, 8);
      l_[rg] = l_[rg] * al + ps;
    }
    #pragma unroll
    for (int dj = 0; dj < 4; ++dj)
      #pragma unroll
      for (int rg = 0; rg < 4; ++rg) o_[dj][rg] *= alpha_[rg];

    __builtin_amdgcn_s_setprio(1);
    #pragma unroll
    for (int kk = 0; kk < 2; ++kk) {
      s16x8 pf = *(const s16x8*)
          &PsL[wid][r16 * 64 + (((kk * 4 + g4) ^ (r16 & 7)) * 8)];
      #pragma unroll
      for (int dj = 0; dj < 4; ++dj) {
        s16x8 vf = *(const s16x8*)
            &VtL[(dj * 16 + r16) * 72 + kk * 32 + g4 * 8];
        o_[dj] = __builtin_amdgcn_mfma_f32_16x16x32_bf16(pf, vf, o_[dj], 0, 0, 0);
      }
    }
    __builtin_amdgcn_s_setprio(0);
  }

  #pragma unroll
  for (int rg = 0; rg < 4; ++rg) {
    int qa = q0 + wid * 16 + g4 * 4 + rg;
    if (qa < T_) {
      float inv = 1.f / l_[rg];
      unsigned short* ob = out + (size_t)(b * T_ + qa) * D_ + h * 64;
      #pragma unroll
      for (int dj = 0; dj < 4; ++dj)
        ob[dj * 16 + r16] = f2bf(o_[dj][rg] * inv);
    }
  }
}

// ---------------------------------------------------------------------------
// xb = bf16( LayerNorm(xb + r) * w + b )  — single residual.
// ---------------------------------------------------------------------------
__global__ __launch_bounds__(256) void ln_res_kernel(
    unsigned short* __restrict__ xb, const unsigned short* __restrict__ r,
    const float* __restrict__ w, const float* __restrict__ b) {
  __shared__ float red[4];
  int row = blockIdx.x, tid = threadIdx.x;
  size_t off = (size_t)row * D_ + tid * 4;
  ushort4 xv = *(const ushort4*)&xb[off];
  ushort4 rv = *(const ushort4*)&r[off];
  float v0 = bf2f(xv.x) + bf2f(rv.x), v1 = bf2f(xv.y) + bf2f(rv.y);
  float v2 = bf2f(xv.z) + bf2f(rv.z), v3 = bf2f(xv.w) + bf2f(rv.w);

  float s = v0 + v1 + v2 + v3;
  #pragma unroll
  for (int o = 1; o < 64; o <<= 1) s += __shfl_xor(s, o);
  if ((tid & 63) == 0) red[tid >> 6] = s;
  __syncthreads();
  float mu = (red[0] + red[1] + red[2] + red[3]) * (1.f / 1024.f);
  __syncthreads();

  float d0 = v0 - mu, d1 = v1 - mu, d2 = v2 - mu, d3 = v3 - mu;
  float ss = d0 * d0 + d1 * d1 + d2 * d2 + d3 * d3;
  #pragma unroll
  for (int o = 1; o < 64; o <<= 1) ss += __shfl_xor(ss, o);
  if ((tid & 63) == 0) red[tid >> 6] = ss;
  __syncthreads();
  float var = (red[0] + red[1] + red[2] + red[3]) * (1.f / 1024.f);
  float rs = rsqrtf(var + 1e-5f);

  float4 wv = *(const float4*)&w[tid * 4];
  float4 bv = *(const float4*)&b[tid * 4];
  float o0 = d0 * rs * wv.x + bv.x, o1 = d1 * rs * wv.y + bv.y;
  float o2 = d2 * rs * wv.z + bv.z, o3 = d3 * rs * wv.w + bv.w;
  unsigned long long pk = (unsigned long long)f2bf(o0)
      | ((unsigned long long)f2bf(o1) << 16)
      | ((unsigned long long)f2bf(o2) << 32)
      | ((unsigned long long)f2bf(o3) << 48);
  *(unsigned long long*)&xb[off] = pk;
}

// ---------------------------------------------------------------------------
// xb = bf16( LayerNorm(xb + r1 + r2) * w + b ) — split-K partials combined.
// r2 = r1 + M_PAD*D_.
// ---------------------------------------------------------------------------
__global__ __launch_bounds__(256) void ln_res2_kernel(
    unsigned short* __restrict__ xb, const unsigned short* __restrict__ r,
    const float* __restrict__ w, const float* __restrict__ b) {
  __shared__ float red[4];
  int row = blockIdx.x, tid = threadIdx.x;
  size_t off = (size_t)row * D_ + tid * 4;
  ushort4 xv = *(const ushort4*)&xb[off];
  ushort4 rv = *(const ushort4*)&r[off];
  ushort4 sv4 = *(const ushort4*)&r[off + (size_t)M_PAD * D_];
  float v0 = bf2f(xv.x) + bf2f(rv.x) + bf2f(sv4.x);
  float v1 = bf2f(xv.y) + bf2f(rv.y) + bf2f(sv4.y);
  float v2 = bf2f(xv.z) + bf2f(rv.z) + bf2f(sv4.z);
  float v3 = bf2f(xv.w) + bf2f(rv.w) + bf2f(sv4.w);

  float s = v0 + v1 + v2 + v3;
  #pragma unroll
  for (int o = 1; o < 64; o <<= 1) s += __shfl_xor(s, o);
  if ((tid & 63) == 0) red[tid >> 6] = s;
  __syncthreads();
  float mu = (red[0] + red[1] + red[2] + red[3]) * (1.f / 1024.f);
  __syncthreads();

  float d0 = v0 - mu, d1 = v1 - mu, d2 = v2 - mu, d3 = v3 - mu;
  float ss = d0 * d0 + d1 * d1 + d2 * d2 + d3 * d3;
  #pragma unroll
  for (int o = 1; o < 64; o <<= 1) ss += __shfl_xor(ss, o);
  if ((tid & 63) == 0) red[tid >> 6] = ss;
  __syncthreads();
  float var = (red[0] + red[1] + red[2] + red[3]) * (1.f / 1024.f);
  float rs = rsqrtf(var + 1e-5f);

  float4 wv = *(const float4*)&w[tid * 4];
  float4 bv = *(const float4*)&b[tid * 4];
  float o0 = d0 * rs * wv.x + bv.x, o1 = d1 * rs * wv.y + bv.y;
  float o2 = d2 * rs * wv.z + bv.z, o3 = d3 * rs * wv.w + bv.w;
  unsigned long long pk = (unsigned long long)f2bf(o0)
      | ((unsigned long long)f2bf(o1) << 16)
      | ((unsigned long long)f2bf(o2) << 32)
      | ((unsigned long long)f2bf(o3) << 48);
  *(unsigned long long*)&xb[off] = pk;
}

extern "C" void kernel_launch(void* const* d_in, const int* in_sizes, int n_in,
                              void* d_out, int out_size, void* d_ws, size_t ws_size,
                              hipStream_t stream) {
  const int* text       = (const int*)d_in[0];
  const int* audio      = (const int*)d_in[1];
  const int* enrolled   = (const int*)d_in[2];
  const int* tl_b       = (const int*)d_in[3];
  const int* al_b       = (const int*)d_in[4];
  const float* text_emb = (const float*)d_in[5];
  const float* audio_emb= (const float*)d_in[6];
  const float* sa_in_w  = (const float*)d_in[7];
  const float* sa_in_b  = (const float*)d_in[8];
  const float* sa_out_w = (const float*)d_in[9];
  const float* sa_out_b = (const float*)d_in[10];
  const float* ca_in_w  = (const float*)d_in[11];
  const float* ca_in_b  = (const float*)d_in[12];
  const float* ca_out_w = (const float*)d_in[13];
  const float* ca_out_b = (const float*)d_in[14];
  const float* ff1_w    = (const float*)d_in[15];
  const float* ff1_b    = (const float*)d_in[16];
  const float* ff2_w    = (const float*)d_in[17];
  const float* ff2_b    = (const float*)d_in[18];
  const float* ln1_w    = (const float*)d_in[19];
  const float* ln1_b    = (const float*)d_in[20];
  const float* ln2_w    = (const float*)d_in[21];
  const float* ln2_b    = (const float*)d_in[22];
  const float* ln3_w    = (const float*)d_in[23];
  const float* ln3_b    = (const float*)d_in[24];
  const float* out_w    = (const float*)d_in[25];
  const float* out_b    = (const float*)d_in[26];

  char* p = (char*)d_ws;
  unsigned short* tmpb = (unsigned short*)p;  p += (size_t)2 * M_PAD * D_ * 2;  // 2 partials
  unsigned short* xb = (unsigned short*)p;    p += (size_t)M_PAD * D_ * 2;
  unsigned short* memb = (unsigned short*)p;  p += (size_t)M_PAD * D_ * 2;
  unsigned short* qkv = (unsigned short*)p;   p += (size_t)M_PAD * FF_ * 2;
  unsigned short* attnb = (unsigned short*)p; p += (size_t)M_PAD * D_ * 2;
  unsigned short* wbuf = (unsigned short*)p;  p += (size_t)16777216 * 2;
  unsigned short* outwb = (unsigned short*)p; p += (size_t)1048576 * 2;
  unsigned short* ckv  = (unsigned short*)p;  p += (size_t)M_PAD * NKV * 2;
  unsigned short* wckv = (unsigned short*)p;  p += (size_t)NKV * D_ * 2;
  float* cbias = (float*)p;                   p += (size_t)NKV * 4;
  bool fused = ((size_t)(p - (char*)d_ws)) <= ws_size;

  unsigned short* w_sa_qkv = wbuf;
  unsigned short* w_sa_o   = wbuf + 3145728;
  unsigned short* w_ca_qkv = wbuf + 4194304;
  unsigned short* w_ca_o   = wbuf + 7340032;
  unsigned short* w_ff1    = wbuf + 8388608;
  unsigned short* w_ff2    = wbuf + 12582912;

  embed_kernel<<<M_PAD, 256, 0, stream>>>(text, audio, enrolled, tl_b, al_b,
                                          text_emb, audio_emb, xb, memb, attnb);
  cvt_kernel<<<512, 256, 0, stream>>>(out_w, outwb, 131072);

  if (fused) {
    cvt_ckv_w<<<NKV, 256, 0, stream>>>(ca_in_w, wckv);
    cvt_ckv_b<<<NKV / 256, 256, 0, stream>>>(ca_in_b, cbias);
    gemm_8w<0, 1, 1><<<dim3(NKV / 256, M_PAD / 256), 512, 0, stream>>>(
        memb, D_, wckv, D_, cbias, nullptr, ckv, NKV, M_PAD, D_);
  }

  for (int l = 0; l < L_; ++l) {
    const float* sa_in_w_l  = sa_in_w  + (size_t)l * 3 * D_ * D_;
    const float* sa_in_b_l  = sa_in_b  + (size_t)l * 3 * D_;
    const float* sa_out_w_l = sa_out_w + (size_t)l * D_ * D_;
    const float* sa_out_b_l = sa_out_b + (size_t)l * D_;
    const float* ca_in_w_l  = ca_in_w  + (size_t)l * 3 * D_ * D_;
    const float* ca_in_b_l  = ca_in_b  + (size_t)l * 3 * D_;
    const float* ca_out_w_l = ca_out_w + (size_t)l * D_ * D_;
    const float* ca_out_b_l = ca_out_b + (size_t)l * D_;
    const float* ff1_w_l    = ff1_w    + (size_t)l * FF_ * D_;
    const float* ff1_b_l    = ff1_b    + (size_t)l * FF_;
    const float* ff2_w_l    = ff2_w    + (size_t)l * D_ * FF_;
    const float* ff2_b_l    = ff2_b    + (size_t)l * D_;

    cvt_layer_kernel<<<8192, 256, 0, stream>>>(sa_in_w_l, sa_out_w_l, ca_in_w_l,
                                               ca_out_w_l, ff1_w_l, ff2_w_l, wbuf);

    // ---- self attention ----
    gemm_8w<0, 1, 1><<<dim3(3 * D_ / 256, M_PAD / 256), 512, 0, stream>>>(
        xb, D_, w_sa_qkv, D_, sa_in_b_l, nullptr, qkv, 3 * D_, M_PAD, D_);
    attn_mfma<true><<<dim3(7, B_ * H_), 512, 0, stream>>>(
        qkv, 3 * D_, qkv + D_, qkv + 2 * D_, 3 * D_, attnb);
    gemm_8w128<0, 1, 0, 1><<<dim3(D_ / 128, M_PAD / 128, 2), 512, 0, stream>>>(
        attnb, D_, w_sa_o, D_, sa_out_b_l, nullptr, tmpb, D_, M_PAD, D_ / 2);
    ln_res2_kernel<<<M_TOK, 256, 0, stream>>>(xb, tmpb, ln1_w + l * D_, ln1_b + l * D_);

    // ---- cross attention ----
    gemm_8w128<0, 1, 0, 0><<<dim3(D_ / 128, M_PAD / 128), 512, 0, stream>>>(
        xb, D_, w_ca_qkv, D_, ca_in_b_l, nullptr, qkv, 3 * D_, M_PAD, D_);   // q
    if (fused) {
      attn_mfma<false><<<dim3(7, B_ * H_), 512, 0, stream>>>(
          qkv, 3 * D_, ckv + (size_t)l * 2 * D_, ckv + (size_t)l * 2 * D_ + D_,
          NKV, attnb);
    } else {
      attn_mfma<false><<<dim3(7, B_ * H_), 512, 0, stream>>>(
          qkv, 3 * D_, qkv + D_, qkv + 2 * D_, 3 * D_, attnb);
    }
    gemm_8w128<0, 1, 0, 1><<<dim3(D_ / 128, M_PAD / 128, 2), 512, 0, stream>>>(
        attnb, D_, w_ca_o, D_, ca_out_b_l, nullptr, tmpb, D_, M_PAD, D_ / 2);
    ln_res2_kernel<<<M_TOK, 256, 0, stream>>>(xb, tmpb, ln2_w + l * D_, ln2_b + l * D_);

    // ---- feed forward ----
    gemm_8w<1, 1, 1><<<dim3(FF_ / 256, M_PAD / 256), 512, 0, stream>>>(
        xb, D_, w_ff1, D_, ff1_b_l, nullptr, qkv, FF_, M_PAD, D_);
    gemm_8w128<0, 1, 1, 1><<<dim3(D_ / 128, M_PAD / 128, 2), 512, 0, stream>>>(
        qkv, FF_, w_ff2, FF_, ff2_b_l, nullptr, tmpb, D_, M_PAD, FF_ / 2);
    ln_res2_kernel<<<M_TOK, 256, 0, stream>>>(xb, tmpb, ln3_w + l * D_, ln3_b + l * D_);
  }

  // final projection -> d_out (fp32), only real rows
  gemm_8w128<0, 0, 0, 0><<<dim3(D_ / 128, M_PAD / 128), 512, 0, stream>>>(
      xb, D_, outwb, D_, out_b, (float*)d_out, nullptr, D_, M_TOK, D_);
}